// Round 4
// baseline (2008.413 us; speedup 1.0000x reference)
//
#include <hip/hip_runtime.h>
#include <cstdint>
#include <cstddef>

// ---------------------------------------------------------------------------
// StaticGNN fused pipeline, fp32, round 4: dst-sorted fused attention +
// fused classifier. N=50000, E=400000, ND=128, ED=64, HID=128.
// ---------------------------------------------------------------------------

static inline int cdiv(int a, int b) { return (a + b - 1) / b; }

// ---------------------------------------------------------------------------
// CSR build
// ---------------------------------------------------------------------------
__global__ void count_deg(const int* __restrict__ src, const int* __restrict__ dst,
                          int* __restrict__ dsrc, int* __restrict__ ddst, int E) {
  int t = blockIdx.x * blockDim.x + threadIdx.x;
  if (t < E) {
    atomicAdd(&dsrc[src[t]], 1);
    atomicAdd(&ddst[dst[t]], 1);
  }
}

__global__ __launch_bounds__(1024) void scan_pair(
    const int* __restrict__ degA, const int* __restrict__ degB,
    int* __restrict__ rowA, int* __restrict__ rowB, int* __restrict__ curA,
    int* __restrict__ curB, int N) {
  __shared__ int part[1024];
  int tid = threadIdx.x;
  int chunk = (N + 1023) / 1024;
  for (int arr = 0; arr < 2; arr++) {
    const int* deg = arr ? degB : degA;
    int* row = arr ? rowB : rowA;
    int* cur = arr ? curB : curA;
    int lo = tid * chunk, hi = min(lo + chunk, N);
    int s = 0;
    for (int i = lo; i < hi; i++) s += deg[i];
    part[tid] = s;
    __syncthreads();
    for (int off = 1; off < 1024; off <<= 1) {
      int v = (tid >= off) ? part[tid - off] : 0;
      __syncthreads();
      if (tid >= off) part[tid] += v;
      __syncthreads();
    }
    int run = (tid == 0) ? 0 : part[tid - 1];
    for (int i = lo; i < hi; i++) {
      row[i] = run;
      cur[i] = run;
      run += deg[i];
    }
    if (tid == 1023) row[N] = part[1023];
    __syncthreads();
  }
}

// row_ext[i] = row_dst[i] + i (self-loop appended at end of each segment)
__global__ void ext_fix(const int* __restrict__ row_dst, int* __restrict__ row_ext,
                        int* __restrict__ cur_ext, int* __restrict__ ext_eid,
                        int* __restrict__ ext_dst, int E, int N) {
  int i = blockIdx.x * blockDim.x + threadIdx.x;
  if (i <= N) row_ext[i] = row_dst[i] + i;
  if (i < N) {
    cur_ext[i] = row_dst[i] + i;
    int pos = row_dst[i + 1] + i;  // row_ext[i+1]-1
    ext_eid[pos] = E + i;
    ext_dst[pos] = i;
  }
}

__global__ void scatter_eid(const int* __restrict__ src, const int* __restrict__ dst,
                            int* __restrict__ csrc, int* __restrict__ cext,
                            int* __restrict__ esrc, int* __restrict__ ext_eid,
                            int* __restrict__ ext_dst, int E) {
  int t = blockIdx.x * blockDim.x + threadIdx.x;
  if (t < E) {
    int p = atomicAdd(&csrc[src[t]], 1);
    esrc[p] = t;
    int d = dst[t];
    int q = atomicAdd(&cext[d], 1);
    ext_eid[q] = t;
    ext_dst[q] = d;
  }
}

// ---------------------------------------------------------------------------
// Virtual 3-way concatenated A operand.
// ---------------------------------------------------------------------------
struct ASrc {
  const float *p0, *p1, *p2;
  int ld0, ld1, ld2, k0, k1;
};
__device__ __forceinline__ float loadA(const ASrc& a, int m, int k) {
  if (k < a.k0) return a.p0[(size_t)m * a.ld0 + k];
  if (k < a.k1) return a.p1[(size_t)m * a.ld1 + (k - a.k0)];
  return a.p2[(size_t)m * a.ld2 + (k - a.k1)];
}
__device__ __forceinline__ int regionOf(const ASrc& a, int k) {
  return k < a.k0 ? 0 : (k < a.k1 ? 1 : 2);
}

// ---------------------------------------------------------------------------
// Generic tiled GEMM (as round 3): 64x128 tile, 4x8 micro-tile.
// ---------------------------------------------------------------------------
template <int ACT>
__global__ __launch_bounds__(256) void gemm_tiled(
    ASrc A, const float* __restrict__ B, int ldb, const float* __restrict__ bias,
    float* __restrict__ C, int ldc, int M, int K) {
  __shared__ __align__(16) float as[64 * 68];
  __shared__ __align__(16) float bs[64 * 128];
  __shared__ float bsh[128];
  int tid = threadIdx.x;
  int m0 = blockIdx.x * 64;
  int n0 = blockIdx.y * 128;
  if (tid < 128) bsh[tid] = bias ? bias[n0 + tid] : 0.f;
  int er = tid >> 4, cc = tid & 15;
  float acc[4][8] = {};
  for (int kc = 0; kc < K; kc += 64) {
    __syncthreads();
    {
      int row = tid & 63, kq = tid >> 6;
      int gm = m0 + row;
      bool fastc = (kc + 64 <= K) && (regionOf(A, kc) == regionOf(A, kc + 63)) &&
                   (gm < M);
      if (fastc) {
        int r = regionOf(A, kc);
        const float* p;
        int ld, koff;
        if (r == 0) { p = A.p0; ld = A.ld0; koff = 0; }
        else if (r == 1) { p = A.p1; ld = A.ld1; koff = A.k0; }
        else { p = A.p2; ld = A.ld2; koff = A.k1; }
        const float* rp = p + (size_t)gm * ld + (kc - koff) + kq * 16;
#pragma unroll
        for (int q = 0; q < 4; q++) {
          float4 v = *(const float4*)(rp + q * 4);
          int kl = kq * 16 + q * 4;
          as[(kl + 0) * 68 + row] = v.x;
          as[(kl + 1) * 68 + row] = v.y;
          as[(kl + 2) * 68 + row] = v.z;
          as[(kl + 3) * 68 + row] = v.w;
        }
      } else {
#pragma unroll
        for (int q = 0; q < 16; q++) {
          int kl = kq * 16 + q;
          int kk = kc + kl;
          as[kl * 68 + row] = (gm < M && kk < K) ? loadA(A, gm, kk) : 0.f;
        }
      }
    }
    {
#pragma unroll
      for (int i = 0; i < 8; i++) {
        int idx = tid + i * 256;
        int k = idx >> 5, c4 = (idx & 31) * 4;
        int kk = kc + k;
        float4 v;
        if (kk < K) v = *(const float4*)&B[(size_t)kk * ldb + n0 + c4];
        else v = make_float4(0.f, 0.f, 0.f, 0.f);
        *(float4*)&bs[k * 128 + c4] = v;
      }
    }
    __syncthreads();
#pragma unroll 4
    for (int k = 0; k < 64; k++) {
      float4 av = *(const float4*)&as[k * 68 + er * 4];
      float4 b0 = *(const float4*)&bs[k * 128 + cc * 4];
      float4 b1 = *(const float4*)&bs[k * 128 + 64 + cc * 4];
      float aa[4] = {av.x, av.y, av.z, av.w};
      float bb[8] = {b0.x, b0.y, b0.z, b0.w, b1.x, b1.y, b1.z, b1.w};
#pragma unroll
      for (int i2 = 0; i2 < 4; i2++)
#pragma unroll
        for (int j = 0; j < 8; j++) acc[i2][j] += aa[i2] * bb[j];
    }
  }
#pragma unroll
  for (int i2 = 0; i2 < 4; i2++) {
    int row = m0 + er * 4 + i2;
    if (row >= M) continue;
#pragma unroll
    for (int h = 0; h < 2; h++) {
      int c = h * 64 + cc * 4;
      float4 v;
      v.x = acc[i2][h * 4 + 0] + bsh[c + 0];
      v.y = acc[i2][h * 4 + 1] + bsh[c + 1];
      v.z = acc[i2][h * 4 + 2] + bsh[c + 2];
      v.w = acc[i2][h * 4 + 3] + bsh[c + 3];
      if (ACT == 1) {
        v.x = fmaxf(v.x, 0.f);
        v.y = fmaxf(v.y, 0.f);
        v.z = fmaxf(v.z, 0.f);
        v.w = fmaxf(v.w, 0.f);
      }
      *(float4*)&C[(size_t)row * ldc + n0 + c] = v;
    }
  }
}

// ---------------------------------------------------------------------------
// gather-mean (side 0: x_out over src-CSR; side 1: x_in + lattr over ext-CSR
// skipping trailing self-loop)
// ---------------------------------------------------------------------------
__global__ __launch_bounds__(256) void gather_mean(
    const int* __restrict__ row_src, const int* __restrict__ eid_src,
    const int* __restrict__ row_ext, const int* __restrict__ ext_eid,
    const float* __restrict__ emb, const float* __restrict__ ea,
    float* __restrict__ xout, float* __restrict__ xin, float* __restrict__ lattr,
    int N) {
  int lane = threadIdx.x & 63, wid = threadIdx.x >> 6;
  int n = blockIdx.x * 4 + wid;
  int side = blockIdx.y;
  if (n >= N) return;
  int lo, hi;
  const int* eid;
  if (side) { lo = row_ext[n]; hi = row_ext[n + 1] - 1; eid = ext_eid; }
  else { lo = row_src[n]; hi = row_src[n + 1]; eid = eid_src; }
  float a0 = 0.f, a1 = 0.f, la = 0.f;
  for (int j = lo; j < hi; j++) {
    int e = eid[j];
    float2 v = *(const float2*)&emb[(size_t)e * 128 + lane * 2];
    a0 += v.x;
    a1 += v.y;
    if (side) la += ea[(size_t)e * 64 + lane];
  }
  float r = 1.f / fmaxf((float)(hi - lo), 1.f);
  float* ob = side ? xin : xout;
  float2 o = make_float2(a0 * r, a1 * r);
  *(float2*)&ob[(size_t)n * 128 + lane * 2] = o;
  if (side) lattr[(size_t)n * 64 + lane] = la * r;
}

// ---------------------------------------------------------------------------
// Fused attention: per 64-ext-edge tile (dst-sorted), per head slab:
// eaw GEMM -> logit -> a=exp(logit) -> segmented aggregation of a*xl[s]
// into agg[dst] (one atomicAdd per segment per col) + denom[dst].
// ---------------------------------------------------------------------------
template <int H>
__global__ __launch_bounds__(256) void attn_fused_tiled(
    const float* __restrict__ xl, const float* __restrict__ xr,
    const int* __restrict__ ext_eid, const int* __restrict__ ext_dst,
    const int* __restrict__ src, const float* __restrict__ ea,
    const float* __restrict__ lattr, const float* __restrict__ we,
    const float* __restrict__ att, float* __restrict__ agg,
    float* __restrict__ denom, int E, int E2) {
  constexpr int HC = H * 128;
  __shared__ __align__(16) float as[64 * 68];
  __shared__ __align__(16) float bs[64 * 128];
  __shared__ float atts[128];
  __shared__ float alds[64];
  __shared__ int sidx[64], didx[64];
  int tid = threadIdx.x;
  int i0 = blockIdx.x * 64;
  int head = blockIdx.y;
  int n0 = head * 128;
  if (tid < 128) atts[tid] = att[n0 + tid];
  if (tid < 64) {
    int gi = i0 + tid;
    int s = 0, d = -1;
    if (gi < E2) {
      int e = ext_eid[gi];
      d = ext_dst[gi];
      s = (e < E) ? src[e] : (e - E);
    }
    sidx[tid] = s;
    didx[tid] = d;
  }
  {  // stage A (ext-edge rows, K=64, k-major)
    int row = tid & 63, kq = tid >> 6;
    int gi = i0 + row;
    if (gi < E2) {
      int e = ext_eid[gi];
      const float* ap = (e < E) ? ea + (size_t)e * 64 : lattr + (size_t)(e - E) * 64;
      const float* rp = ap + kq * 16;
#pragma unroll
      for (int q = 0; q < 4; q++) {
        float4 v = *(const float4*)(rp + q * 4);
        int kl = kq * 16 + q * 4;
        as[(kl + 0) * 68 + row] = v.x;
        as[(kl + 1) * 68 + row] = v.y;
        as[(kl + 2) * 68 + row] = v.z;
        as[(kl + 3) * 68 + row] = v.w;
      }
    } else {
#pragma unroll
      for (int q = 0; q < 16; q++) as[(kq * 16 + q) * 68 + row] = 0.f;
    }
  }
  {  // stage we slab
#pragma unroll
    for (int i = 0; i < 8; i++) {
      int idx = tid + i * 256;
      int k = idx >> 5, c4 = (idx & 31) * 4;
      float4 v = *(const float4*)&we[(size_t)k * HC + n0 + c4];
      *(float4*)&bs[k * 128 + c4] = v;
    }
  }
  __syncthreads();
  int er = tid >> 4, cc = tid & 15;
  float acc[4][8] = {};
#pragma unroll 4
  for (int k = 0; k < 64; k++) {
    float4 av = *(const float4*)&as[k * 68 + er * 4];
    float4 b0 = *(const float4*)&bs[k * 128 + cc * 4];
    float4 b1 = *(const float4*)&bs[k * 128 + 64 + cc * 4];
    float aa[4] = {av.x, av.y, av.z, av.w};
    float bb[8] = {b0.x, b0.y, b0.z, b0.w, b1.x, b1.y, b1.z, b1.w};
#pragma unroll
    for (int i2 = 0; i2 < 4; i2++)
#pragma unroll
      for (int j = 0; j < 8; j++) acc[i2][j] += aa[i2] * bb[j];
  }
  // logit + exp epilogue
#pragma unroll
  for (int i2 = 0; i2 < 4; i2++) {
    int r = er * 4 + i2;
    int gi = i0 + r;
    float ps = 0.f;
    if (gi < E2) {
      int s = sidx[r], d = didx[r];
#pragma unroll
      for (int h = 0; h < 2; h++) {
        int c = h * 64 + cc * 4;
        float4 xlv = *(const float4*)&xl[(size_t)s * HC + n0 + c];
        float4 xrv = *(const float4*)&xr[(size_t)d * HC + n0 + c];
        float e0 = acc[i2][h * 4 + 0] + xlv.x + xrv.x;
        float e1 = acc[i2][h * 4 + 1] + xlv.y + xrv.y;
        float e2 = acc[i2][h * 4 + 2] + xlv.z + xrv.z;
        float e3 = acc[i2][h * 4 + 3] + xlv.w + xrv.w;
        e0 = e0 > 0.f ? e0 : 0.2f * e0;
        e1 = e1 > 0.f ? e1 : 0.2f * e1;
        e2 = e2 > 0.f ? e2 : 0.2f * e2;
        e3 = e3 > 0.f ? e3 : 0.2f * e3;
        ps += e0 * atts[c + 0] + e1 * atts[c + 1] + e2 * atts[c + 2] +
              e3 * atts[c + 3];
      }
    }
    ps += __shfl_xor(ps, 1);
    ps += __shfl_xor(ps, 2);
    ps += __shfl_xor(ps, 4);
    ps += __shfl_xor(ps, 8);
    if (cc == 0) alds[r] = (gi < E2) ? __expf(ps) : 0.f;
  }
  __syncthreads();
  // segmented aggregation: 128 col-threads per row-half
  {
    int half = tid >> 7;
    int c = tid & 127;
    int r0 = half * 32, r1 = r0 + 32;
    float accv = 0.f, da = 0.f;
    int cur = didx[r0];
    for (int r = r0; r < r1; r++) {
      int d = didx[r];
      if (d != cur) {
        if (cur >= 0) {
          atomicAdd(&agg[(size_t)cur * HC + n0 + c], accv);
          if (c == 0) atomicAdd(&denom[cur * H + head], da);
        }
        accv = 0.f;
        da = 0.f;
        cur = d;
      }
      float a = alds[r];
      accv += a * xl[(size_t)sidx[r] * HC + n0 + c];
      if (c == 0) da += a;
    }
    if (cur >= 0) {
      atomicAdd(&agg[(size_t)cur * HC + n0 + c], accv);
      if (c == 0) atomicAdd(&denom[cur * H + head], da);
    }
  }
}

// ---------------------------------------------------------------------------
// post: h = elu(LN(headmean(agg/denom) + bias) * g + b)
// ---------------------------------------------------------------------------
template <int H>
__global__ __launch_bounds__(256) void post_ln2(
    const float* __restrict__ agg, const float* __restrict__ denom,
    const float* __restrict__ bias, const float* __restrict__ gam,
    const float* __restrict__ bet, float* __restrict__ out, int N) {
  int lane = threadIdx.x & 63, wid = threadIdx.x >> 6;
  int n = blockIdx.x * 4 + wid;
  if (n >= N) return;
  int c = lane * 2;
  float v0, v1;
  if (H == 2) {
    float r0 = 1.f / fmaxf(denom[n * 2], 1e-16f);
    float r1 = 1.f / fmaxf(denom[n * 2 + 1], 1e-16f);
    v0 = (agg[(size_t)n * 256 + c] * r0 + agg[(size_t)n * 256 + 128 + c] * r1) * 0.5f;
    v1 = (agg[(size_t)n * 256 + c + 1] * r0 + agg[(size_t)n * 256 + 129 + c] * r1) * 0.5f;
  } else {
    float r0 = 1.f / fmaxf(denom[n], 1e-16f);
    v0 = agg[(size_t)n * 128 + c] * r0;
    v1 = agg[(size_t)n * 128 + c + 1] * r0;
  }
  v0 += bias[c];
  v1 += bias[c + 1];
  float s = v0 + v1;
#pragma unroll
  for (int m = 1; m < 64; m <<= 1) s += __shfl_xor(s, m);
  float mu = s * (1.f / 128.f);
  float d0 = v0 - mu, d1 = v1 - mu;
  float vs = d0 * d0 + d1 * d1;
#pragma unroll
  for (int m = 1; m < 64; m <<= 1) vs += __shfl_xor(vs, m);
  float rstd = rsqrtf(vs * (1.f / 128.f) + 1e-5f);
  float y0 = d0 * rstd * gam[c] + bet[c];
  float y1 = d1 * rstd * gam[c + 1] + bet[c + 1];
  out[(size_t)n * 128 + c] = y0 > 0.f ? y0 : expm1f(y0);
  out[(size_t)n * 128 + c + 1] = y1 > 0.f ? y1 : expm1f(y1);
}

// ---------------------------------------------------------------------------
// Fused classifier: phase1 t1 = relu(ea@Wc + P[s] + Q[d] + c1b) (regs),
// LDS round-trip, phase2 t2 = relu(t1@c2w + c2b), out = t2.c3w + c3b.
// ---------------------------------------------------------------------------
__global__ __launch_bounds__(256) void classifier_fused(
    const float* __restrict__ ea, const float* __restrict__ Wc,
    const int* __restrict__ src, const int* __restrict__ dst,
    const float* __restrict__ P, const float* __restrict__ Q,
    const float* __restrict__ c1b, const float* __restrict__ c2w,
    const float* __restrict__ c2b, const float* __restrict__ c3w,
    const float* __restrict__ c3b, float* __restrict__ out, int E) {
  __shared__ __align__(16) float u[12800];  // as(4352)+bs(8192) / t1s(8704)+c2s(4096)
  __shared__ float bsh[128];
  __shared__ float c2bs[64], c3ws[64];
  __shared__ int sidx[64], didx[64];
  float* as = u;
  float* bs = u + 4352;
  int tid = threadIdx.x;
  int e0 = blockIdx.x * 64;
  if (tid < 128) bsh[tid] = c1b[tid];
  if (tid < 64) {
    c2bs[tid] = c2b[tid];
    c3ws[tid] = c3w[tid];
    int gi = e0 + tid;
    sidx[tid] = gi < E ? src[gi] : 0;
    didx[tid] = gi < E ? dst[gi] : 0;
  }
  {  // stage ea rows
    int row = tid & 63, kq = tid >> 6;
    int gi = e0 + row;
    if (gi < E) {
      const float* rp = ea + (size_t)gi * 64 + kq * 16;
#pragma unroll
      for (int q = 0; q < 4; q++) {
        float4 v = *(const float4*)(rp + q * 4);
        int kl = kq * 16 + q * 4;
        as[(kl + 0) * 68 + row] = v.x;
        as[(kl + 1) * 68 + row] = v.y;
        as[(kl + 2) * 68 + row] = v.z;
        as[(kl + 3) * 68 + row] = v.w;
      }
    } else {
#pragma unroll
      for (int q = 0; q < 16; q++) as[(kq * 16 + q) * 68 + row] = 0.f;
    }
  }
  {  // stage Wc [64][128]
#pragma unroll
    for (int i = 0; i < 8; i++) {
      int idx = tid + i * 256;
      int k = idx >> 5, c4 = (idx & 31) * 4;
      *(float4*)&bs[k * 128 + c4] = *(const float4*)&Wc[(size_t)k * 128 + c4];
    }
  }
  __syncthreads();
  int er = tid >> 4, cc = tid & 15;
  float acc[4][8] = {};
#pragma unroll 4
  for (int k = 0; k < 64; k++) {
    float4 av = *(const float4*)&as[k * 68 + er * 4];
    float4 b0 = *(const float4*)&bs[k * 128 + cc * 4];
    float4 b1 = *(const float4*)&bs[k * 128 + 64 + cc * 4];
    float aa[4] = {av.x, av.y, av.z, av.w};
    float bb[8] = {b0.x, b0.y, b0.z, b0.w, b1.x, b1.y, b1.z, b1.w};
#pragma unroll
    for (int i2 = 0; i2 < 4; i2++)
#pragma unroll
      for (int j = 0; j < 8; j++) acc[i2][j] += aa[i2] * bb[j];
  }
  // apply P/Q/bias + relu in registers
  float t1v[4][8];
#pragma unroll
  for (int i2 = 0; i2 < 4; i2++) {
    int r = er * 4 + i2;
    int gi = e0 + r;
    if (gi < E) {
      int s = sidx[r], d = didx[r];
#pragma unroll
      for (int h = 0; h < 2; h++) {
        int c = h * 64 + cc * 4;
        float4 pv = *(const float4*)&P[(size_t)s * 128 + c];
        float4 qv = *(const float4*)&Q[(size_t)d * 128 + c];
        t1v[i2][h * 4 + 0] = fmaxf(acc[i2][h * 4 + 0] + pv.x + qv.x + bsh[c + 0], 0.f);
        t1v[i2][h * 4 + 1] = fmaxf(acc[i2][h * 4 + 1] + pv.y + qv.y + bsh[c + 1], 0.f);
        t1v[i2][h * 4 + 2] = fmaxf(acc[i2][h * 4 + 2] + pv.z + qv.z + bsh[c + 2], 0.f);
        t1v[i2][h * 4 + 3] = fmaxf(acc[i2][h * 4 + 3] + pv.w + qv.w + bsh[c + 3], 0.f);
      }
    } else {
#pragma unroll
      for (int j = 0; j < 8; j++) t1v[i2][j] = 0.f;
    }
  }
  __syncthreads();  // as/bs dead
  // write t1 k-major: t1s[col*68 + row]
  float* t1s = u;          // 128*68 = 8704
  float* c2s = u + 8704;   // 64*64 = 4096
#pragma unroll
  for (int i2 = 0; i2 < 4; i2++) {
    int r = er * 4 + i2;
#pragma unroll
    for (int h = 0; h < 2; h++)
#pragma unroll
      for (int j = 0; j < 4; j++)
        t1s[(h * 64 + cc * 4 + j) * 68 + r] = t1v[i2][h * 4 + j];
  }
  float acc2[4][4] = {};
  for (int kc = 0; kc < 128; kc += 64) {
    __syncthreads();
#pragma unroll
    for (int i = 0; i < 4; i++) {
      int idx = tid + i * 256;
      int k = idx >> 4, c4 = (idx & 15) * 4;
      *(float4*)&c2s[k * 64 + c4] = *(const float4*)&c2w[(size_t)(kc + k) * 64 + c4];
    }
    __syncthreads();
#pragma unroll 4
    for (int k = 0; k < 64; k++) {
      float4 av = *(const float4*)&t1s[(kc + k) * 68 + er * 4];
      float4 bv = *(const float4*)&c2s[k * 64 + cc * 4];
      float aa[4] = {av.x, av.y, av.z, av.w};
      float bb[4] = {bv.x, bv.y, bv.z, bv.w};
#pragma unroll
      for (int i2 = 0; i2 < 4; i2++)
#pragma unroll
        for (int j = 0; j < 4; j++) acc2[i2][j] += aa[i2] * bb[j];
    }
  }
  float c3b0 = c3b[0];
#pragma unroll
  for (int i2 = 0; i2 < 4; i2++) {
    int gi = e0 + er * 4 + i2;
    float ps = 0.f;
#pragma unroll
    for (int j = 0; j < 4; j++) {
      float t2v = fmaxf(acc2[i2][j] + c2bs[cc * 4 + j], 0.f);
      ps += t2v * c3ws[cc * 4 + j];
    }
    ps += __shfl_xor(ps, 1);
    ps += __shfl_xor(ps, 2);
    ps += __shfl_xor(ps, 4);
    ps += __shfl_xor(ps, 8);
    if (cc == 0 && gi < E) out[gi] = ps + c3b0;
  }
}

// ---------------------------------------------------------------------------
extern "C" void kernel_launch(void* const* d_in, const int* in_sizes, int n_in,
                              void* d_out, int out_size, void* d_ws, size_t ws_size,
                              hipStream_t stream) {
  const int N = in_sizes[1] / 2;   // node_stats [N,2]
  const int E = in_sizes[3] / 64;  // edge_attr [E,64]
  const int E2 = E + N;

  const float* node_stats = (const float*)d_in[1];
  const int* src = (const int*)d_in[2];
  const int* dst = (const int*)d_in[2] + E;
  const float* edge_attr = (const float*)d_in[3];
  const float* epw = (const float*)d_in[4];
  const float* epb = (const float*)d_in[5];
  const float* g1wl = (const float*)d_in[6];
  const float* g1wr = (const float*)d_in[7];
  const float* g1we = (const float*)d_in[8];
  const float* g1att = (const float*)d_in[9];
  const float* g1b = (const float*)d_in[10];
  const float* n1g = (const float*)d_in[11];
  const float* n1b = (const float*)d_in[12];
  const float* g2wl = (const float*)d_in[13];
  const float* g2wr = (const float*)d_in[14];
  const float* g2we = (const float*)d_in[15];
  const float* g2att = (const float*)d_in[16];
  const float* g2b = (const float*)d_in[17];
  const float* n2g = (const float*)d_in[18];
  const float* n2b = (const float*)d_in[19];
  const float* c1w = (const float*)d_in[20];
  const float* c1b = (const float*)d_in[21];
  const float* c2w = (const float*)d_in[22];
  const float* c2b = (const float*)d_in[23];
  const float* c3w = (const float*)d_in[24];
  const float* c3b = (const float*)d_in[25];
  float* out = (float*)d_out;

  // workspace arena
  float* w = (float*)d_ws;
  size_t o = 0;
  auto alloc = [&](size_t n) { float* p = w + o; o += n; return p; };
  float* xout = alloc((size_t)N * 128);     // later: xl2, then P
  float* xin = alloc((size_t)N * 128);      // later: xr2, then Q
  float* lattr = alloc((size_t)N * 64);
  float* agg = alloc((size_t)N * 256);      // + denom contiguous (one memset)
  float* dn = alloc((size_t)N * 2);
  int* row_src = (int*)alloc((size_t)(N + 1));
  int* row_dst = (int*)alloc((size_t)(N + 1));
  int* row_ext = (int*)alloc((size_t)(N + 1));
  int* deg_src = (int*)alloc((size_t)N);    // deg pair contiguous (memset)
  int* deg_dst = (int*)alloc((size_t)N);
  int* cur_src = (int*)alloc((size_t)N);
  int* cur_ext = (int*)alloc((size_t)N);
  int* eid_src = (int*)alloc((size_t)E);
  int* ext_eid = (int*)alloc((size_t)E2);
  int* ext_dst = (int*)alloc((size_t)E2);
  float* R = alloc((size_t)E * 128);        // emb, then xl1|xr1
  float* emb = R;
  float* xl1 = R;
  float* xr1 = R + (size_t)N * 256;
  float* h1 = xr1;   // xr1 dead after fused layer-1
  float* xl2 = xout;
  float* xr2 = xin;
  float* h2 = xl1;   // xl1 dead after fused layer-1
  float* P = xout;
  float* Q = xin;

  // ---- stage 0: CSR + extended (self-loop) CSR ----
  hipMemsetAsync(deg_src, 0, (size_t)2 * N * sizeof(int), stream);
  count_deg<<<cdiv(E, 256), 256, 0, stream>>>(src, dst, deg_src, deg_dst, E);
  scan_pair<<<1, 1024, 0, stream>>>(deg_src, deg_dst, row_src, row_dst, cur_src,
                                    cur_ext, N);
  ext_fix<<<cdiv(N + 1, 256), 256, 0, stream>>>(row_dst, row_ext, cur_ext, ext_eid,
                                                ext_dst, E, N);
  scatter_eid<<<cdiv(E, 256), 256, 0, stream>>>(src, dst, cur_src, cur_ext,
                                                eid_src, ext_eid, ext_dst, E);

  // ---- stage 1: emb = relu(ea@epw+epb); gather means ----
  {
    ASrc a{edge_attr, nullptr, nullptr, 64, 0, 0, 64, 64};
    gemm_tiled<1><<<dim3(cdiv(E, 64), 1), 256, 0, stream>>>(a, epw, 128, epb, emb,
                                                            128, E, 64);
  }
  gather_mean<<<dim3(cdiv(N, 4), 2), 256, 0, stream>>>(
      row_src, eid_src, row_ext, ext_eid, emb, edge_attr, xout, xin, lattr, N);

  // ---- stage 2: xl1/xr1 = xi @ g1wl / g1wr (K=258, Nc=256) ----
  {
    ASrc a{xout, xin, node_stats, 128, 128, 2, 128, 256};
    dim3 g(cdiv(N, 64), 2);
    gemm_tiled<0><<<g, 256, 0, stream>>>(a, g1wl, 256, nullptr, xl1, 256, N, 258);
    gemm_tiled<0><<<g, 256, 0, stream>>>(a, g1wr, 256, nullptr, xr1, 256, N, 258);
  }

  // ---- stage 3: GATv2 layer 1 (H=2) fused ----
  hipMemsetAsync(agg, 0, (size_t)N * 258 * sizeof(float), stream);
  attn_fused_tiled<2><<<dim3(cdiv(E2, 64), 2), 256, 0, stream>>>(
      xl1, xr1, ext_eid, ext_dst, src, edge_attr, lattr, g1we, g1att, agg, dn, E,
      E2);
  post_ln2<2><<<cdiv(N, 4), 256, 0, stream>>>(agg, dn, g1b, n1g, n1b, h1, N);

  // ---- stage 4: xl2/xr2 = h1 @ g2wl / g2wr ----
  {
    ASrc a{h1, nullptr, nullptr, 128, 0, 0, 128, 128};
    dim3 g(cdiv(N, 64), 1);
    gemm_tiled<0><<<g, 256, 0, stream>>>(a, g2wl, 128, nullptr, xl2, 128, N, 128);
    gemm_tiled<0><<<g, 256, 0, stream>>>(a, g2wr, 128, nullptr, xr2, 128, N, 128);
  }

  // ---- stage 5: GATv2 layer 2 (H=1) fused ----
  hipMemsetAsync(agg, 0, (size_t)N * 258 * sizeof(float), stream);
  attn_fused_tiled<1><<<dim3(cdiv(E2, 64), 1), 256, 0, stream>>>(
      xl2, xr2, ext_eid, ext_dst, src, edge_attr, lattr, g2we, g2att, agg, dn, E,
      E2);
  post_ln2<1><<<cdiv(N, 4), 256, 0, stream>>>(agg, dn, g2b, n2g, n2b, h2, N);

  // ---- stage 6: classifier ----
  {
    ASrc a{h2, nullptr, nullptr, 128, 0, 0, 128, 128};
    dim3 g(cdiv(N, 64), 1);
    gemm_tiled<0><<<g, 256, 0, stream>>>(a, c1w, 128, nullptr, P, 128, N, 128);
    gemm_tiled<0><<<g, 256, 0, stream>>>(a, c1w + 128 * 128, 128, nullptr, Q, 128,
                                         N, 128);
  }
  classifier_fused<<<cdiv(E, 64), 256, 0, stream>>>(
      edge_attr, c1w + 256 * 128, src, dst, P, Q, c1b, c2w, c2b, c3w, c3b, out, E);
}

// Round 5
// 1937.157 us; speedup vs baseline: 1.0368x; 1.0368x over previous
//
#include <hip/hip_runtime.h>
#include <cstdint>
#include <cstddef>

// ---------------------------------------------------------------------------
// StaticGNN fused pipeline, round 5: R3 split attention + bf16 xl/xr storage
// (fp32 accumulate), single-pass ea staging, fused classifier.
// N=50000, E=400000, ND=128, ED=64, HID=128.
// ---------------------------------------------------------------------------

static inline int cdiv(int a, int b) { return (a + b - 1) / b; }

__device__ __forceinline__ float bf2f(unsigned short u) {
  return __uint_as_float(((unsigned)u) << 16);
}
__device__ __forceinline__ unsigned short f2bf(float f) {
  unsigned b = __float_as_uint(f);
  return (unsigned short)((b + 0x7FFFu + ((b >> 16) & 1u)) >> 16);
}

// ---------------------------------------------------------------------------
// CSR build (src CSR + extended dst CSR with self-loop at end of each segment)
// ---------------------------------------------------------------------------
__global__ void count_deg(const int* __restrict__ src, const int* __restrict__ dst,
                          int* __restrict__ dsrc, int* __restrict__ ddst, int E) {
  int t = blockIdx.x * blockDim.x + threadIdx.x;
  if (t < E) {
    atomicAdd(&dsrc[src[t]], 1);
    atomicAdd(&ddst[dst[t]], 1);
  }
}

__global__ __launch_bounds__(1024) void scan_pair(
    const int* __restrict__ degA, const int* __restrict__ degB,
    int* __restrict__ rowA, int* __restrict__ rowB, int* __restrict__ curA,
    int* __restrict__ curB, int N) {
  __shared__ int part[1024];
  int tid = threadIdx.x;
  int chunk = (N + 1023) / 1024;
  for (int arr = 0; arr < 2; arr++) {
    const int* deg = arr ? degB : degA;
    int* row = arr ? rowB : rowA;
    int* cur = arr ? curB : curA;
    int lo = tid * chunk, hi = min(lo + chunk, N);
    int s = 0;
    for (int i = lo; i < hi; i++) s += deg[i];
    part[tid] = s;
    __syncthreads();
    for (int off = 1; off < 1024; off <<= 1) {
      int v = (tid >= off) ? part[tid - off] : 0;
      __syncthreads();
      if (tid >= off) part[tid] += v;
      __syncthreads();
    }
    int run = (tid == 0) ? 0 : part[tid - 1];
    for (int i = lo; i < hi; i++) {
      row[i] = run;
      cur[i] = run;
      run += deg[i];
    }
    if (tid == 1023) row[N] = part[1023];
    __syncthreads();
  }
}

// row_ext[i] = row_dst[i] + i; self-loop (eid E+i) at end of each segment
__global__ void ext_fix(const int* __restrict__ row_dst, int* __restrict__ row_ext,
                        int* __restrict__ cur_ext, int* __restrict__ ext_eid,
                        int E, int N) {
  int i = blockIdx.x * blockDim.x + threadIdx.x;
  if (i <= N) row_ext[i] = row_dst[i] + i;
  if (i < N) {
    cur_ext[i] = row_dst[i] + i;
    ext_eid[row_dst[i + 1] + i] = E + i;
  }
}

__global__ void scatter_eid(const int* __restrict__ src, const int* __restrict__ dst,
                            int* __restrict__ csrc, int* __restrict__ cext,
                            int* __restrict__ esrc, int* __restrict__ ext_eid,
                            int E) {
  int t = blockIdx.x * blockDim.x + threadIdx.x;
  if (t < E) {
    int p = atomicAdd(&csrc[src[t]], 1);
    esrc[p] = t;
    int q = atomicAdd(&cext[dst[t]], 1);
    ext_eid[q] = t;
  }
}

// ---------------------------------------------------------------------------
// Virtual 3-way concatenated A operand.
// ---------------------------------------------------------------------------
struct ASrc {
  const float *p0, *p1, *p2;
  int ld0, ld1, ld2, k0, k1;
};
__device__ __forceinline__ float loadA(const ASrc& a, int m, int k) {
  if (k < a.k0) return a.p0[(size_t)m * a.ld0 + k];
  if (k < a.k1) return a.p1[(size_t)m * a.ld1 + (k - a.k0)];
  return a.p2[(size_t)m * a.ld2 + (k - a.k1)];
}
__device__ __forceinline__ int regionOf(const ASrc& a, int k) {
  return k < a.k0 ? 0 : (k < a.k1 ? 1 : 2);
}

// ---------------------------------------------------------------------------
// Tiled GEMM: 64x128 tile, 4x8 micro-tile. ACT: 0=none 1=relu.
// OBF: 0 -> fp32 C, 1 -> bf16 (ushort) C. ldc in elements of output type.
// ---------------------------------------------------------------------------
template <int ACT, int OBF>
__global__ __launch_bounds__(256) void gemm_tiled(
    ASrc A, const float* __restrict__ B, int ldb, const float* __restrict__ bias,
    void* __restrict__ Cv, int ldc, int M, int K) {
  __shared__ __align__(16) float as[64 * 68];
  __shared__ __align__(16) float bs[64 * 128];
  __shared__ float bsh[128];
  int tid = threadIdx.x;
  int m0 = blockIdx.x * 64;
  int n0 = blockIdx.y * 128;
  if (tid < 128) bsh[tid] = bias ? bias[n0 + tid] : 0.f;
  int er = tid >> 4, cc = tid & 15;
  float acc[4][8] = {};
  for (int kc = 0; kc < K; kc += 64) {
    __syncthreads();
    {
      int row = tid & 63, kq = tid >> 6;
      int gm = m0 + row;
      bool fastc = (kc + 64 <= K) && (regionOf(A, kc) == regionOf(A, kc + 63)) &&
                   (gm < M);
      if (fastc) {
        int r = regionOf(A, kc);
        const float* p;
        int ld, koff;
        if (r == 0) { p = A.p0; ld = A.ld0; koff = 0; }
        else if (r == 1) { p = A.p1; ld = A.ld1; koff = A.k0; }
        else { p = A.p2; ld = A.ld2; koff = A.k1; }
        const float* rp = p + (size_t)gm * ld + (kc - koff) + kq * 16;
#pragma unroll
        for (int q = 0; q < 4; q++) {
          float4 v = *(const float4*)(rp + q * 4);
          int kl = kq * 16 + q * 4;
          as[(kl + 0) * 68 + row] = v.x;
          as[(kl + 1) * 68 + row] = v.y;
          as[(kl + 2) * 68 + row] = v.z;
          as[(kl + 3) * 68 + row] = v.w;
        }
      } else {
#pragma unroll
        for (int q = 0; q < 16; q++) {
          int kl = kq * 16 + q;
          int kk = kc + kl;
          as[kl * 68 + row] = (gm < M && kk < K) ? loadA(A, gm, kk) : 0.f;
        }
      }
    }
    {
#pragma unroll
      for (int i = 0; i < 8; i++) {
        int idx = tid + i * 256;
        int k = idx >> 5, c4 = (idx & 31) * 4;
        int kk = kc + k;
        float4 v;
        if (kk < K) v = *(const float4*)&B[(size_t)kk * ldb + n0 + c4];
        else v = make_float4(0.f, 0.f, 0.f, 0.f);
        *(float4*)&bs[k * 128 + c4] = v;
      }
    }
    __syncthreads();
#pragma unroll 4
    for (int k = 0; k < 64; k++) {
      float4 av = *(const float4*)&as[k * 68 + er * 4];
      float4 b0 = *(const float4*)&bs[k * 128 + cc * 4];
      float4 b1 = *(const float4*)&bs[k * 128 + 64 + cc * 4];
      float aa[4] = {av.x, av.y, av.z, av.w};
      float bb[8] = {b0.x, b0.y, b0.z, b0.w, b1.x, b1.y, b1.z, b1.w};
#pragma unroll
      for (int i2 = 0; i2 < 4; i2++)
#pragma unroll
        for (int j = 0; j < 8; j++) acc[i2][j] += aa[i2] * bb[j];
    }
  }
#pragma unroll
  for (int i2 = 0; i2 < 4; i2++) {
    int row = m0 + er * 4 + i2;
    if (row >= M) continue;
#pragma unroll
    for (int h = 0; h < 2; h++) {
      int c = h * 64 + cc * 4;
      float v[4];
#pragma unroll
      for (int j = 0; j < 4; j++) {
        v[j] = acc[i2][h * 4 + j] + bsh[c + j];
        if (ACT == 1) v[j] = fmaxf(v[j], 0.f);
      }
      if (OBF) {
        ushort4 o;
        o.x = f2bf(v[0]); o.y = f2bf(v[1]); o.z = f2bf(v[2]); o.w = f2bf(v[3]);
        *(ushort4*)&((unsigned short*)Cv)[(size_t)row * ldc + n0 + c] = o;
      } else {
        float4 o = make_float4(v[0], v[1], v[2], v[3]);
        *(float4*)&((float*)Cv)[(size_t)row * ldc + n0 + c] = o;
      }
    }
  }
}

// ---------------------------------------------------------------------------
// gather-mean (side 0: x_out over src-CSR; side 1: x_in + lattr over ext-CSR
// excluding the trailing self-loop)
// ---------------------------------------------------------------------------
__global__ __launch_bounds__(256) void gather_mean(
    const int* __restrict__ row_src, const int* __restrict__ eid_src,
    const int* __restrict__ row_ext, const int* __restrict__ ext_eid,
    const float* __restrict__ emb, const float* __restrict__ ea,
    float* __restrict__ xout, float* __restrict__ xin, float* __restrict__ lattr,
    int N) {
  int lane = threadIdx.x & 63, wid = threadIdx.x >> 6;
  int n = blockIdx.x * 4 + wid;
  int side = blockIdx.y;
  if (n >= N) return;
  int lo, hi;
  const int* eid;
  if (side) { lo = row_ext[n]; hi = row_ext[n + 1] - 1; eid = ext_eid; }
  else { lo = row_src[n]; hi = row_src[n + 1]; eid = eid_src; }
  float a0 = 0.f, a1 = 0.f, la = 0.f;
  for (int j = lo; j < hi; j++) {
    int e = eid[j];
    float2 v = *(const float2*)&emb[(size_t)e * 128 + lane * 2];
    a0 += v.x;
    a1 += v.y;
    if (side) la += ea[(size_t)e * 64 + lane];
  }
  float r = 1.f / fmaxf((float)(hi - lo), 1.f);
  float* ob = side ? xin : xout;
  *(float2*)&ob[(size_t)n * 128 + lane * 2] = make_float2(a0 * r, a1 * r);
  if (side) lattr[(size_t)n * 64 + lane] = la * r;
}

// ---------------------------------------------------------------------------
// attn_logits<H>: per 64-ext-edge tile (plain edge order): M = ea2 @ we,
// epilogue leaky(M + xl[s] + xr[d]) . att -> lg[i*H+head]. Heads looped
// inside the block (ea staged once). xl/xr in bf16.
// ---------------------------------------------------------------------------
template <int H>
__global__ __launch_bounds__(256) void attn_logits_tiled(
    const unsigned short* __restrict__ xl, const unsigned short* __restrict__ xr,
    const int* __restrict__ src, const int* __restrict__ dst,
    const float* __restrict__ ea, const float* __restrict__ lattr,
    const float* __restrict__ we, const float* __restrict__ att,
    float* __restrict__ lg, int E, int N) {
  constexpr int HC = H * 128;
  __shared__ __align__(16) float as[64 * 68];
  __shared__ __align__(16) float bs[64 * 128];
  __shared__ float atts[128];
  __shared__ int sidx[64], didx[64];
  int tid = threadIdx.x;
  int E2 = E + N;
  int i0 = blockIdx.x * 64;
  if (tid < 64) {
    int gi = i0 + tid;
    int s = 0, d = 0;
    if (gi < E2) {
      if (gi < E) { s = src[gi]; d = dst[gi]; }
      else { s = d = gi - E; }
    }
    sidx[tid] = s;
    didx[tid] = d;
  }
  {  // stage A once (contiguous rows)
    int row = tid & 63, kq = tid >> 6;
    int gi = i0 + row;
    if (gi < E2) {
      const float* ap =
          (gi < E) ? ea + (size_t)gi * 64 : lattr + (size_t)(gi - E) * 64;
      const float* rp = ap + kq * 16;
#pragma unroll
      for (int q = 0; q < 4; q++) {
        float4 v = *(const float4*)(rp + q * 4);
        int kl = kq * 16 + q * 4;
        as[(kl + 0) * 68 + row] = v.x;
        as[(kl + 1) * 68 + row] = v.y;
        as[(kl + 2) * 68 + row] = v.z;
        as[(kl + 3) * 68 + row] = v.w;
      }
    } else {
#pragma unroll
      for (int q = 0; q < 16; q++) as[(kq * 16 + q) * 68 + row] = 0.f;
    }
  }
  int er = tid >> 4, cc = tid & 15;
  for (int head = 0; head < H; head++) {
    int n0 = head * 128;
    __syncthreads();
    if (tid < 128) atts[tid] = att[n0 + tid];
    {
#pragma unroll
      for (int i = 0; i < 8; i++) {
        int idx = tid + i * 256;
        int k = idx >> 5, c4 = (idx & 31) * 4;
        *(float4*)&bs[k * 128 + c4] = *(const float4*)&we[(size_t)k * HC + n0 + c4];
      }
    }
    __syncthreads();
    float acc[4][8] = {};
#pragma unroll 4
    for (int k = 0; k < 64; k++) {
      float4 av = *(const float4*)&as[k * 68 + er * 4];
      float4 b0 = *(const float4*)&bs[k * 128 + cc * 4];
      float4 b1 = *(const float4*)&bs[k * 128 + 64 + cc * 4];
      float aa[4] = {av.x, av.y, av.z, av.w};
      float bb[8] = {b0.x, b0.y, b0.z, b0.w, b1.x, b1.y, b1.z, b1.w};
#pragma unroll
      for (int i2 = 0; i2 < 4; i2++)
#pragma unroll
        for (int j = 0; j < 8; j++) acc[i2][j] += aa[i2] * bb[j];
    }
#pragma unroll
    for (int i2 = 0; i2 < 4; i2++) {
      int r = er * 4 + i2;
      int gi = i0 + r;
      float ps = 0.f;
      if (gi < E2) {
        int s = sidx[r], d = didx[r];
#pragma unroll
        for (int h = 0; h < 2; h++) {
          int c = h * 64 + cc * 4;
          ushort4 xlu = *(const ushort4*)&xl[(size_t)s * HC + n0 + c];
          ushort4 xru = *(const ushort4*)&xr[(size_t)d * HC + n0 + c];
          float e0 = acc[i2][h * 4 + 0] + bf2f(xlu.x) + bf2f(xru.x);
          float e1 = acc[i2][h * 4 + 1] + bf2f(xlu.y) + bf2f(xru.y);
          float e2 = acc[i2][h * 4 + 2] + bf2f(xlu.z) + bf2f(xru.z);
          float e3 = acc[i2][h * 4 + 3] + bf2f(xlu.w) + bf2f(xru.w);
          e0 = e0 > 0.f ? e0 : 0.2f * e0;
          e1 = e1 > 0.f ? e1 : 0.2f * e1;
          e2 = e2 > 0.f ? e2 : 0.2f * e2;
          e3 = e3 > 0.f ? e3 : 0.2f * e3;
          ps += e0 * atts[c + 0] + e1 * atts[c + 1] + e2 * atts[c + 2] +
                e3 * atts[c + 3];
        }
      }
      ps += __shfl_xor(ps, 1);
      ps += __shfl_xor(ps, 2);
      ps += __shfl_xor(ps, 4);
      ps += __shfl_xor(ps, 8);
      if (cc == 0 && gi < E2) lg[(size_t)gi * H + head] = ps;
    }
  }
}

// ---------------------------------------------------------------------------
// attn_fused<H>: softmax + aggregate + head-mean + bias + LN + ELU.
// Wave per destination node; ext-CSR gather (self-loop included). xl bf16.
// ---------------------------------------------------------------------------
template <int H>
__global__ __launch_bounds__(256) void attn_fused(
    const unsigned short* __restrict__ xl, const float* __restrict__ lg,
    const int* __restrict__ row_ext, const int* __restrict__ ext_eid,
    const int* __restrict__ src, const float* __restrict__ bias,
    const float* __restrict__ gam, const float* __restrict__ bet,
    float* __restrict__ hout, int E, int N) {
  constexpr int HC = H * 128;
  constexpr int CPL = HC / 64;
  int lane = threadIdx.x & 63, wid = threadIdx.x >> 6;
  int n = blockIdx.x * 4 + wid;
  if (n >= N) return;
  int lo = row_ext[n], hi = row_ext[n + 1];
  int myh = (H == 2) ? (lane >> 5) : 0;
  int colbase = (H == 2) ? (myh * 128 + (lane & 31) * 4) : (lane * 2);
  float m = -3.4e38f;
  for (int j = lo; j < hi; j++) m = fmaxf(m, lg[(size_t)ext_eid[j] * H + myh]);
  float asum = 0.f;
  float acc[CPL] = {};
  for (int j = lo; j < hi; j++) {
    int e = ext_eid[j];
    int s = (e < E) ? src[e] : (e - E);
    float a = __expf(lg[(size_t)e * H + myh] - m);
    asum += a;
    const unsigned short* xp = &xl[(size_t)s * HC + colbase];
    if (H == 2) {
      ushort4 u = *(const ushort4*)xp;
      acc[0] += a * bf2f(u.x);
      acc[1] += a * bf2f(u.y);
      acc[2] += a * bf2f(u.z);
      acc[3] += a * bf2f(u.w);
    } else {
      acc[0] += a * bf2f(xp[0]);
      acc[1] += a * bf2f(xp[1]);
    }
  }
  float inv = 1.f / fmaxf(asum, 1e-16f);
#pragma unroll
  for (int k = 0; k < CPL; k++) acc[k] *= inv;
  int ch;
  if (H == 2) {
#pragma unroll
    for (int k = 0; k < CPL; k++) acc[k] = (acc[k] + __shfl_xor(acc[k], 32)) * 0.5f;
    ch = (lane & 31) * CPL;
  } else {
    ch = lane * CPL;
  }
#pragma unroll
  for (int k = 0; k < CPL; k++) acc[k] += bias[ch + k];
  float s = 0.f;
#pragma unroll
  for (int k = 0; k < CPL; k++) s += acc[k];
#pragma unroll
  for (int mm = 1; mm < 64; mm <<= 1) s += __shfl_xor(s, mm);
  constexpr float dupn = (H == 2) ? 256.f : 128.f;
  float mu = s / dupn;
  float vs = 0.f;
#pragma unroll
  for (int k = 0; k < CPL; k++) {
    acc[k] -= mu;
    vs += acc[k] * acc[k];
  }
#pragma unroll
  for (int mm = 1; mm < 64; mm <<= 1) vs += __shfl_xor(vs, mm);
  float rstd = rsqrtf(vs / dupn + 1e-5f);
  float y[CPL];
#pragma unroll
  for (int k = 0; k < CPL; k++) {
    float v = acc[k] * rstd * gam[ch + k] + bet[ch + k];
    y[k] = v > 0.f ? v : expm1f(v);
  }
  if (H == 2) {
    if (lane < 32)
      *(float4*)&hout[(size_t)n * 128 + ch] = make_float4(y[0], y[1], y[2], y[3]);
  } else {
    *(float2*)&hout[(size_t)n * 128 + ch] = make_float2(y[0], y[1]);
  }
}

// ---------------------------------------------------------------------------
// Fused classifier (round 4): t1 in regs -> LDS k-major -> t2 -> out.
// ---------------------------------------------------------------------------
__global__ __launch_bounds__(256) void classifier_fused(
    const float* __restrict__ ea, const float* __restrict__ Wc,
    const int* __restrict__ src, const int* __restrict__ dst,
    const float* __restrict__ P, const float* __restrict__ Q,
    const float* __restrict__ c1b, const float* __restrict__ c2w,
    const float* __restrict__ c2b, const float* __restrict__ c3w,
    const float* __restrict__ c3b, float* __restrict__ out, int E) {
  __shared__ __align__(16) float u[12800];
  __shared__ float bsh[128];
  __shared__ float c2bs[64], c3ws[64];
  __shared__ int sidx[64], didx[64];
  float* as = u;
  float* bs = u + 4352;
  int tid = threadIdx.x;
  int e0 = blockIdx.x * 64;
  if (tid < 128) bsh[tid] = c1b[tid];
  if (tid < 64) {
    c2bs[tid] = c2b[tid];
    c3ws[tid] = c3w[tid];
    int gi = e0 + tid;
    sidx[tid] = gi < E ? src[gi] : 0;
    didx[tid] = gi < E ? dst[gi] : 0;
  }
  {
    int row = tid & 63, kq = tid >> 6;
    int gi = e0 + row;
    if (gi < E) {
      const float* rp = ea + (size_t)gi * 64 + kq * 16;
#pragma unroll
      for (int q = 0; q < 4; q++) {
        float4 v = *(const float4*)(rp + q * 4);
        int kl = kq * 16 + q * 4;
        as[(kl + 0) * 68 + row] = v.x;
        as[(kl + 1) * 68 + row] = v.y;
        as[(kl + 2) * 68 + row] = v.z;
        as[(kl + 3) * 68 + row] = v.w;
      }
    } else {
#pragma unroll
      for (int q = 0; q < 16; q++) as[(kq * 16 + q) * 68 + row] = 0.f;
    }
  }
  {
#pragma unroll
    for (int i = 0; i < 8; i++) {
      int idx = tid + i * 256;
      int k = idx >> 5, c4 = (idx & 31) * 4;
      *(float4*)&bs[k * 128 + c4] = *(const float4*)&Wc[(size_t)k * 128 + c4];
    }
  }
  __syncthreads();
  int er = tid >> 4, cc = tid & 15;
  float acc[4][8] = {};
#pragma unroll 4
  for (int k = 0; k < 64; k++) {
    float4 av = *(const float4*)&as[k * 68 + er * 4];
    float4 b0 = *(const float4*)&bs[k * 128 + cc * 4];
    float4 b1 = *(const float4*)&bs[k * 128 + 64 + cc * 4];
    float aa[4] = {av.x, av.y, av.z, av.w};
    float bb[8] = {b0.x, b0.y, b0.z, b0.w, b1.x, b1.y, b1.z, b1.w};
#pragma unroll
    for (int i2 = 0; i2 < 4; i2++)
#pragma unroll
      for (int j = 0; j < 8; j++) acc[i2][j] += aa[i2] * bb[j];
  }
  float t1v[4][8];
#pragma unroll
  for (int i2 = 0; i2 < 4; i2++) {
    int r = er * 4 + i2;
    int gi = e0 + r;
    if (gi < E) {
      int s = sidx[r], d = didx[r];
#pragma unroll
      for (int h = 0; h < 2; h++) {
        int c = h * 64 + cc * 4;
        float4 pv = *(const float4*)&P[(size_t)s * 128 + c];
        float4 qv = *(const float4*)&Q[(size_t)d * 128 + c];
        t1v[i2][h * 4 + 0] = fmaxf(acc[i2][h * 4 + 0] + pv.x + qv.x + bsh[c + 0], 0.f);
        t1v[i2][h * 4 + 1] = fmaxf(acc[i2][h * 4 + 1] + pv.y + qv.y + bsh[c + 1], 0.f);
        t1v[i2][h * 4 + 2] = fmaxf(acc[i2][h * 4 + 2] + pv.z + qv.z + bsh[c + 2], 0.f);
        t1v[i2][h * 4 + 3] = fmaxf(acc[i2][h * 4 + 3] + pv.w + qv.w + bsh[c + 3], 0.f);
      }
    } else {
#pragma unroll
      for (int j = 0; j < 8; j++) t1v[i2][j] = 0.f;
    }
  }
  __syncthreads();
  float* t1s = u;
  float* c2s = u + 8704;
#pragma unroll
  for (int i2 = 0; i2 < 4; i2++) {
    int r = er * 4 + i2;
#pragma unroll
    for (int h = 0; h < 2; h++)
#pragma unroll
      for (int j = 0; j < 4; j++)
        t1s[(h * 64 + cc * 4 + j) * 68 + r] = t1v[i2][h * 4 + j];
  }
  float acc2[4][4] = {};
  for (int kc = 0; kc < 128; kc += 64) {
    __syncthreads();
#pragma unroll
    for (int i = 0; i < 4; i++) {
      int idx = tid + i * 256;
      int k = idx >> 4, c4 = (idx & 15) * 4;
      *(float4*)&c2s[k * 64 + c4] = *(const float4*)&c2w[(size_t)(kc + k) * 64 + c4];
    }
    __syncthreads();
#pragma unroll 4
    for (int k = 0; k < 64; k++) {
      float4 av = *(const float4*)&t1s[(kc + k) * 68 + er * 4];
      float4 bv = *(const float4*)&c2s[k * 64 + cc * 4];
      float aa[4] = {av.x, av.y, av.z, av.w};
      float bb[4] = {bv.x, bv.y, bv.z, bv.w};
#pragma unroll
      for (int i2 = 0; i2 < 4; i2++)
#pragma unroll
        for (int j = 0; j < 4; j++) acc2[i2][j] += aa[i2] * bb[j];
    }
  }
  float c3b0 = c3b[0];
#pragma unroll
  for (int i2 = 0; i2 < 4; i2++) {
    int gi = e0 + er * 4 + i2;
    float ps = 0.f;
#pragma unroll
    for (int j = 0; j < 4; j++) {
      float t2v = fmaxf(acc2[i2][j] + c2bs[cc * 4 + j], 0.f);
      ps += t2v * c3ws[cc * 4 + j];
    }
    ps += __shfl_xor(ps, 1);
    ps += __shfl_xor(ps, 2);
    ps += __shfl_xor(ps, 4);
    ps += __shfl_xor(ps, 8);
    if (cc == 0 && gi < E) out[gi] = ps + c3b0;
  }
}

// ---------------------------------------------------------------------------
extern "C" void kernel_launch(void* const* d_in, const int* in_sizes, int n_in,
                              void* d_out, int out_size, void* d_ws, size_t ws_size,
                              hipStream_t stream) {
  const int N = in_sizes[1] / 2;   // node_stats [N,2]
  const int E = in_sizes[3] / 64;  // edge_attr [E,64]
  const int E2 = E + N;

  const float* node_stats = (const float*)d_in[1];
  const int* src = (const int*)d_in[2];
  const int* dst = (const int*)d_in[2] + E;
  const float* edge_attr = (const float*)d_in[3];
  const float* epw = (const float*)d_in[4];
  const float* epb = (const float*)d_in[5];
  const float* g1wl = (const float*)d_in[6];
  const float* g1wr = (const float*)d_in[7];
  const float* g1we = (const float*)d_in[8];
  const float* g1att = (const float*)d_in[9];
  const float* g1b = (const float*)d_in[10];
  const float* n1g = (const float*)d_in[11];
  const float* n1b = (const float*)d_in[12];
  const float* g2wl = (const float*)d_in[13];
  const float* g2wr = (const float*)d_in[14];
  const float* g2we = (const float*)d_in[15];
  const float* g2att = (const float*)d_in[16];
  const float* g2b = (const float*)d_in[17];
  const float* n2g = (const float*)d_in[18];
  const float* n2b = (const float*)d_in[19];
  const float* c1w = (const float*)d_in[20];
  const float* c1b = (const float*)d_in[21];
  const float* c2w = (const float*)d_in[22];
  const float* c2b = (const float*)d_in[23];
  const float* c3w = (const float*)d_in[24];
  const float* c3b = (const float*)d_in[25];
  float* out = (float*)d_out;

  // workspace arena
  float* w = (float*)d_ws;
  size_t o = 0;
  auto alloc = [&](size_t n) { float* p = w + o; o += n; return p; };
  float* xout = alloc((size_t)N * 128);  // later P
  float* xin = alloc((size_t)N * 128);   // later Q
  float* lattr = alloc((size_t)N * 64);
  float* lg = alloc((size_t)E2 * 2);
  int* row_src = (int*)alloc((size_t)(N + 1));
  int* row_dst = (int*)alloc((size_t)(N + 1));
  int* row_ext = (int*)alloc((size_t)(N + 1));
  int* deg_src = (int*)alloc((size_t)N);  // deg pair contiguous (memset)
  int* deg_dst = (int*)alloc((size_t)N);
  int* cur_src = (int*)alloc((size_t)N);
  int* cur_ext = (int*)alloc((size_t)N);
  int* eid_src = (int*)alloc((size_t)E);
  int* ext_eid = (int*)alloc((size_t)E2);
  float* R = alloc((size_t)E * 128);  // emb, then bf16/fp32 node feature slabs
  float* emb = R;
  unsigned short* xl1b = (unsigned short*)R;                 // N*256 bf16
  unsigned short* xr1b = (unsigned short*)(R + (size_t)N * 128);  // N*256 bf16
  float* h1 = R + (size_t)N * 256;                           // N*128 f32
  float* h2 = R + (size_t)N * 384;                           // N*128 f32
  unsigned short* xl2b = (unsigned short*)(R + (size_t)N * 512);  // N*128 bf16
  unsigned short* xr2b = (unsigned short*)(R + (size_t)N * 576);  // N*128 bf16
  float* P = xout;
  float* Q = xin;

  // ---- stage 0: CSR (src) + extended dst CSR ----
  hipMemsetAsync(deg_src, 0, (size_t)2 * N * sizeof(int), stream);
  count_deg<<<cdiv(E, 256), 256, 0, stream>>>(src, dst, deg_src, deg_dst, E);
  scan_pair<<<1, 1024, 0, stream>>>(deg_src, deg_dst, row_src, row_dst, cur_src,
                                    cur_ext, N);
  ext_fix<<<cdiv(N + 1, 256), 256, 0, stream>>>(row_dst, row_ext, cur_ext,
                                                ext_eid, E, N);
  scatter_eid<<<cdiv(E, 256), 256, 0, stream>>>(src, dst, cur_src, cur_ext,
                                                eid_src, ext_eid, E);

  // ---- stage 1: emb = relu(ea@epw+epb); gather means ----
  {
    ASrc a{edge_attr, nullptr, nullptr, 64, 0, 0, 64, 64};
    gemm_tiled<1, 0><<<dim3(cdiv(E, 64), 1), 256, 0, stream>>>(a, epw, 128, epb,
                                                               emb, 128, E, 64);
  }
  gather_mean<<<dim3(cdiv(N, 4), 2), 256, 0, stream>>>(
      row_src, eid_src, row_ext, ext_eid, emb, edge_attr, xout, xin, lattr, N);

  // ---- stage 2: xl1/xr1 (bf16) = xi @ g1wl / g1wr (K=258, Nc=256) ----
  {
    ASrc a{xout, xin, node_stats, 128, 128, 2, 128, 256};
    dim3 g(cdiv(N, 64), 2);
    gemm_tiled<0, 1><<<g, 256, 0, stream>>>(a, g1wl, 256, nullptr, xl1b, 256, N, 258);
    gemm_tiled<0, 1><<<g, 256, 0, stream>>>(a, g1wr, 256, nullptr, xr1b, 256, N, 258);
  }

  // ---- stage 3: GATv2 layer 1 (H=2) ----
  attn_logits_tiled<2><<<cdiv(E2, 64), 256, 0, stream>>>(
      xl1b, xr1b, src, dst, edge_attr, lattr, g1we, g1att, lg, E, N);
  attn_fused<2><<<cdiv(N, 4), 256, 0, stream>>>(xl1b, lg, row_ext, ext_eid, src,
                                                g1b, n1g, n1b, h1, E, N);

  // ---- stage 4: xl2/xr2 (bf16) = h1 @ g2wl / g2wr ----
  {
    ASrc a{h1, nullptr, nullptr, 128, 0, 0, 128, 128};
    dim3 g(cdiv(N, 64), 1);
    gemm_tiled<0, 1><<<g, 256, 0, stream>>>(a, g2wl, 128, nullptr, xl2b, 128, N, 128);
    gemm_tiled<0, 1><<<g, 256, 0, stream>>>(a, g2wr, 128, nullptr, xr2b, 128, N, 128);
  }

  // ---- stage 5: GATv2 layer 2 (H=1) ----
  attn_logits_tiled<1><<<cdiv(E2, 64), 256, 0, stream>>>(
      xl2b, xr2b, src, dst, edge_attr, lattr, g2we, g2att, lg, E, N);
  attn_fused<1><<<cdiv(N, 4), 256, 0, stream>>>(xl2b, lg, row_ext, ext_eid, src,
                                                g2b, n2g, n2b, h2, E, N);

  // ---- stage 6: classifier ----
  {
    ASrc a{h2, nullptr, nullptr, 128, 0, 0, 128, 128};
    dim3 g(cdiv(N, 64), 1);
    gemm_tiled<0, 0><<<g, 256, 0, stream>>>(a, c1w, 128, nullptr, P, 128, N, 128);
    gemm_tiled<0, 0><<<g, 256, 0, stream>>>(a, c1w + 128 * 128, 128, nullptr, Q,
                                            128, N, 128);
  }
  classifier_fused<<<cdiv(E, 64), 256, 0, stream>>>(
      edge_attr, c1w + 256 * 128, src, dst, P, Q, c1b, c2w, c2b, c3w, c3b, out, E);
}

// Round 6
// 1268.400 us; speedup vs baseline: 1.5834x; 1.5272x over previous
//
#include <hip/hip_runtime.h>
#include <cstdint>
#include <cstddef>

// ---------------------------------------------------------------------------
// StaticGNN fused pipeline, round 6: bf16 MFMA for every GEMM-shaped stage.
// N=50000, E=400000, ND=128, ED=64, HID=128.
// ---------------------------------------------------------------------------

static inline int cdiv(int a, int b) { return (a + b - 1) / b; }

typedef __attribute__((ext_vector_type(8))) short bfrag;   // 8 bf16 (4 VGPRs)
typedef __attribute__((ext_vector_type(4))) float ffrag;   // 4 fp32 acc

__device__ __forceinline__ float bf2f(unsigned short u) {
  return __uint_as_float(((unsigned)u) << 16);
}
__device__ __forceinline__ unsigned short f2bf(float f) {
  unsigned b = __float_as_uint(f);
  return (unsigned short)((b + 0x7FFFu + ((b >> 16) & 1u)) >> 16);
}

// ---------------------------------------------------------------------------
// Weight prep: W[K][Nc] fp32 -> Wt[Nc][KC] bf16 (zero-padded K -> KC).
// ---------------------------------------------------------------------------
struct PrepJobs {
  const float* src[11];
  unsigned short* dst[11];
  int K[11], Nc[11], KC[11], ld[11];
};
__global__ void prep_bt(PrepJobs J) {
  int j = blockIdx.x;
  int K = J.K[j], Nc = J.Nc[j], KC = J.KC[j], ld = J.ld[j];
  const float* S = J.src[j];
  unsigned short* D = J.dst[j];
  for (int n = blockIdx.y; n < Nc; n += gridDim.y)
    for (int t = threadIdx.x; t < KC; t += blockDim.x) {
      float v = (t < K) ? S[(size_t)t * ld + n] : 0.f;
      D[(size_t)n * KC + t] = f2bf(v);
    }
}

// ---------------------------------------------------------------------------
// CSR build (src CSR + extended dst CSR with self-loop at segment end)
// ---------------------------------------------------------------------------
__global__ void count_deg(const int* __restrict__ src, const int* __restrict__ dst,
                          int* __restrict__ dsrc, int* __restrict__ ddst, int E) {
  int t = blockIdx.x * blockDim.x + threadIdx.x;
  if (t < E) {
    atomicAdd(&dsrc[src[t]], 1);
    atomicAdd(&ddst[dst[t]], 1);
  }
}

__global__ __launch_bounds__(1024) void scan_pair(
    const int* __restrict__ degA, const int* __restrict__ degB,
    int* __restrict__ rowA, int* __restrict__ rowB, int* __restrict__ curA,
    int* __restrict__ curB, int N) {
  __shared__ int part[1024];
  int tid = threadIdx.x;
  int chunk = (N + 1023) / 1024;
  for (int arr = 0; arr < 2; arr++) {
    const int* deg = arr ? degB : degA;
    int* row = arr ? rowB : rowA;
    int* cur = arr ? curB : curA;
    int lo = tid * chunk, hi = min(lo + chunk, N);
    int s = 0;
    for (int i = lo; i < hi; i++) s += deg[i];
    part[tid] = s;
    __syncthreads();
    for (int off = 1; off < 1024; off <<= 1) {
      int v = (tid >= off) ? part[tid - off] : 0;
      __syncthreads();
      if (tid >= off) part[tid] += v;
      __syncthreads();
    }
    int run = (tid == 0) ? 0 : part[tid - 1];
    for (int i = lo; i < hi; i++) {
      row[i] = run;
      cur[i] = run;
      run += deg[i];
    }
    if (tid == 1023) row[N] = part[1023];
    __syncthreads();
  }
}

__global__ void ext_fix(const int* __restrict__ row_dst, int* __restrict__ row_ext,
                        int* __restrict__ cur_ext, int* __restrict__ ext_eid,
                        int E, int N) {
  int i = blockIdx.x * blockDim.x + threadIdx.x;
  if (i <= N) row_ext[i] = row_dst[i] + i;
  if (i < N) {
    cur_ext[i] = row_dst[i] + i;
    ext_eid[row_dst[i + 1] + i] = E + i;
  }
}

__global__ void scatter_eid(const int* __restrict__ src, const int* __restrict__ dst,
                            int* __restrict__ csrc, int* __restrict__ cext,
                            int* __restrict__ esrc, int* __restrict__ ext_eid,
                            int E) {
  int t = blockIdx.x * blockDim.x + threadIdx.x;
  if (t < E) {
    int p = atomicAdd(&csrc[src[t]], 1);
    esrc[p] = t;
    int q = atomicAdd(&cext[dst[t]], 1);
    ext_eid[q] = t;
  }
}

// ---------------------------------------------------------------------------
// Virtual 3-way concatenated A operand (fp32 sources).
// ---------------------------------------------------------------------------
struct ASrc {
  const float *p0, *p1, *p2;
  int ld0, ld1, ld2, k0, k1;
};
__device__ __forceinline__ float loadA(const ASrc& a, int m, int k) {
  if (k < a.k0) return a.p0[(size_t)m * a.ld0 + k];
  if (k < a.k1) return a.p1[(size_t)m * a.ld1 + (k - a.k0)];
  return a.p2[(size_t)m * a.ld2 + (k - a.k1)];
}
__device__ __forceinline__ int regionOf(const ASrc& a, int k) {
  return k < a.k0 ? 0 : (k < a.k1 ? 1 : 2);
}

// ---------------------------------------------------------------------------
// MFMA GEMM: C[M, n0..n0+128) = act(A[M,K] @ B + bias). 64x128 tile, 4 waves,
// each wave a 16-row band x 8 col-tiles of 16x16x32 MFMA.
// A: fp32 (ASrc, converted) if ABF=0, bf16 row-major (Abf,lda) if ABF=1.
// Bt: pre-transposed bf16 [Nc][ldbt], ldbt = ceil(K/64)*64, zero-padded.
// ---------------------------------------------------------------------------
template <int ACT, int OBF, int ABF>
__global__ __launch_bounds__(256) void gemm_mfma(
    ASrc A, const unsigned short* __restrict__ Abf, int lda,
    const unsigned short* __restrict__ Bt, int ldbt,
    const float* __restrict__ bias, void* __restrict__ Cv, int ldc, int M, int K) {
  __shared__ __align__(16) unsigned short asb[64 * 72];
  __shared__ __align__(16) unsigned short bsb[128 * 72];
  int tid = threadIdx.x;
  int m0 = blockIdx.x * 64, n0 = blockIdx.y * 128;
  int lane = tid & 63, wave = tid >> 6;
  int quad = lane >> 4, l16 = lane & 15;
  ffrag zero = {0.f, 0.f, 0.f, 0.f};
  ffrag acc[8];
#pragma unroll
  for (int t = 0; t < 8; t++) acc[t] = zero;
  int KC = (K + 63) & ~63;
  for (int kc = 0; kc < KC; kc += 64) {
    __syncthreads();
    {  // stage A -> bf16 LDS [64][72]
      int row = tid & 63, kq = tid >> 6;
      int gm = m0 + row;
      if (ABF) {
        const unsigned short* rp = Abf + (size_t)gm * lda + kc + kq * 16;
        ushort4 z = make_ushort4(0, 0, 0, 0);
#pragma unroll
        for (int q = 0; q < 4; q++) {
          ushort4 v = (gm < M) ? *(const ushort4*)(rp + q * 4) : z;
          *(ushort4*)&asb[row * 72 + kq * 16 + q * 4] = v;
        }
      } else {
        bool fastc = (kc + 64 <= K) && (regionOf(A, kc) == regionOf(A, kc + 63)) &&
                     (gm < M);
        if (fastc) {
          int r = regionOf(A, kc);
          const float* p;
          int ld, koff;
          if (r == 0) { p = A.p0; ld = A.ld0; koff = 0; }
          else if (r == 1) { p = A.p1; ld = A.ld1; koff = A.k0; }
          else { p = A.p2; ld = A.ld2; koff = A.k1; }
          const float* rp = p + (size_t)gm * ld + (kc - koff) + kq * 16;
#pragma unroll
          for (int q = 0; q < 4; q++) {
            float4 v = *(const float4*)(rp + q * 4);
            *(ushort4*)&asb[row * 72 + kq * 16 + q * 4] =
                make_ushort4(f2bf(v.x), f2bf(v.y), f2bf(v.z), f2bf(v.w));
          }
        } else {
#pragma unroll
          for (int q = 0; q < 16; q++) {
            int kk = kc + kq * 16 + q;
            float v = (gm < M && kk < K) ? loadA(A, gm, kk) : 0.f;
            asb[row * 72 + kq * 16 + q] = f2bf(v);
          }
        }
      }
    }
    {  // stage B chunk: Bt rows n0..n0+127, 64 k each
      int n = tid >> 1, hf = tid & 1;
      const ushort4* rp = (const ushort4*)(Bt + (size_t)(n0 + n) * ldbt + kc + hf * 32);
      ushort4* dp = (ushort4*)&bsb[n * 72 + hf * 32];
#pragma unroll
      for (int i = 0; i < 8; i++) dp[i] = rp[i];
    }
    __syncthreads();
    int arow = wave * 16 + l16;
    bfrag a0 = *(const bfrag*)&asb[arow * 72 + quad * 8];
    bfrag a1 = *(const bfrag*)&asb[arow * 72 + 32 + quad * 8];
#pragma unroll
    for (int t = 0; t < 8; t++) {
      int bn = t * 16 + l16;
      bfrag b0 = *(const bfrag*)&bsb[bn * 72 + quad * 8];
      bfrag b1 = *(const bfrag*)&bsb[bn * 72 + 32 + quad * 8];
      acc[t] = __builtin_amdgcn_mfma_f32_16x16x32_bf16(a0, b0, acc[t], 0, 0, 0);
      acc[t] = __builtin_amdgcn_mfma_f32_16x16x32_bf16(a1, b1, acc[t], 0, 0, 0);
    }
  }
  // epilogue: C layout col=lane&15, row=quad*4+reg
#pragma unroll
  for (int t = 0; t < 8; t++) {
    int col = n0 + t * 16 + l16;
    float bv = bias ? bias[col] : 0.f;
#pragma unroll
    for (int r = 0; r < 4; r++) {
      int row = m0 + wave * 16 + quad * 4 + r;
      if (row < M) {
        float v = acc[t][r] + bv;
        if (ACT == 1) v = fmaxf(v, 0.f);
        if (OBF)
          ((unsigned short*)Cv)[(size_t)row * ldc + col] = f2bf(v);
        else
          ((float*)Cv)[(size_t)row * ldc + col] = v;
      }
    }
  }
}

// ---------------------------------------------------------------------------
// gather-mean (emb bf16): side 0 -> x_out over src-CSR; side 1 -> x_in +
// lattr over ext-CSR (excluding trailing self-loop)
// ---------------------------------------------------------------------------
__global__ __launch_bounds__(256) void gather_mean(
    const int* __restrict__ row_src, const int* __restrict__ eid_src,
    const int* __restrict__ row_ext, const int* __restrict__ ext_eid,
    const unsigned short* __restrict__ emb, const float* __restrict__ ea,
    float* __restrict__ xout, float* __restrict__ xin, float* __restrict__ lattr,
    int N) {
  int lane = threadIdx.x & 63, wid = threadIdx.x >> 6;
  int n = blockIdx.x * 4 + wid;
  int side = blockIdx.y;
  if (n >= N) return;
  int lo, hi;
  const int* eid;
  if (side) { lo = row_ext[n]; hi = row_ext[n + 1] - 1; eid = ext_eid; }
  else { lo = row_src[n]; hi = row_src[n + 1]; eid = eid_src; }
  float a0 = 0.f, a1 = 0.f, la = 0.f;
  for (int j = lo; j < hi; j++) {
    int e = eid[j];
    ushort2 v = *(const ushort2*)&emb[(size_t)e * 128 + lane * 2];
    a0 += bf2f(v.x);
    a1 += bf2f(v.y);
    if (side) la += ea[(size_t)e * 64 + lane];
  }
  float r = 1.f / fmaxf((float)(hi - lo), 1.f);
  float* ob = side ? xin : xout;
  *(float2*)&ob[(size_t)n * 128 + lane * 2] = make_float2(a0 * r, a1 * r);
  if (side) lattr[(size_t)n * 64 + lane] = la * r;
}

// ---------------------------------------------------------------------------
// attn_logits_mfma<H>: 64-ext-edge tile; per head slab: MFMA eaw GEMM ->
// LDS roundtrip -> leaky(M + xl[s] + xr[d]) . att -> lg.  xl/xr bf16.
// wet: pre-transposed we [H*128][64] bf16.
// ---------------------------------------------------------------------------
template <int H>
__global__ __launch_bounds__(256) void attn_logits_mfma(
    const unsigned short* __restrict__ xl, const unsigned short* __restrict__ xr,
    const int* __restrict__ src, const int* __restrict__ dst,
    const float* __restrict__ ea, const float* __restrict__ lattr,
    const unsigned short* __restrict__ wet, const float* __restrict__ att,
    float* __restrict__ lg, int E, int N) {
  constexpr int HC = H * 128;
  __shared__ __align__(16) unsigned short asb[64 * 72];
  __shared__ __align__(16) unsigned short bsb[128 * 72];  // reused as Cs[64][136]
  __shared__ float atts[128];
  __shared__ int sidx[64], didx[64];
  unsigned short* Cs = bsb;
  int tid = threadIdx.x;
  int E2 = E + N;
  int i0 = blockIdx.x * 64;
  int lane = tid & 63, wave = tid >> 6, quad = lane >> 4, l16 = lane & 15;
  if (tid < 64) {
    int gi = i0 + tid;
    int s = 0, d = 0;
    if (gi < E2) {
      if (gi < E) { s = src[gi]; d = dst[gi]; }
      else { s = d = gi - E; }
    }
    sidx[tid] = s;
    didx[tid] = d;
  }
  {  // stage A once (contiguous ext-edge rows, fp32 -> bf16)
    int row = tid & 63, kq = tid >> 6;
    int gi = i0 + row;
    if (gi < E2) {
      const float* ap =
          (gi < E) ? ea + (size_t)gi * 64 : lattr + (size_t)(gi - E) * 64;
      const float* rp = ap + kq * 16;
#pragma unroll
      for (int q = 0; q < 4; q++) {
        float4 v = *(const float4*)(rp + q * 4);
        *(ushort4*)&asb[row * 72 + kq * 16 + q * 4] =
            make_ushort4(f2bf(v.x), f2bf(v.y), f2bf(v.z), f2bf(v.w));
      }
    } else {
      ushort4 z = make_ushort4(0, 0, 0, 0);
#pragma unroll
      for (int q = 0; q < 4; q++) *(ushort4*)&asb[row * 72 + kq * 16 + q * 4] = z;
    }
  }
  int er = tid >> 4, cc = tid & 15;
  ffrag zero = {0.f, 0.f, 0.f, 0.f};
  for (int head = 0; head < H; head++) {
    int n0 = head * 128;
    __syncthreads();  // prev epilogue done; A staged (first iter)
    if (tid < 128) atts[tid] = att[n0 + tid];
    {  // stage we slab [128][64]
      int n = tid >> 1, hf = tid & 1;
      const ushort4* rp = (const ushort4*)(wet + (size_t)(n0 + n) * 64 + hf * 32);
      ushort4* dp = (ushort4*)&bsb[n * 72 + hf * 32];
#pragma unroll
      for (int i = 0; i < 8; i++) dp[i] = rp[i];
    }
    __syncthreads();
    int arow = wave * 16 + l16;
    bfrag a0 = *(const bfrag*)&asb[arow * 72 + quad * 8];
    bfrag a1 = *(const bfrag*)&asb[arow * 72 + 32 + quad * 8];
    ffrag acc[8];
#pragma unroll
    for (int t = 0; t < 8; t++) {
      acc[t] = zero;
      int bn = t * 16 + l16;
      bfrag b0 = *(const bfrag*)&bsb[bn * 72 + quad * 8];
      bfrag b1 = *(const bfrag*)&bsb[bn * 72 + 32 + quad * 8];
      acc[t] = __builtin_amdgcn_mfma_f32_16x16x32_bf16(a0, b0, acc[t], 0, 0, 0);
      acc[t] = __builtin_amdgcn_mfma_f32_16x16x32_bf16(a1, b1, acc[t], 0, 0, 0);
    }
    __syncthreads();  // B reads done before Cs overwrite
    {
      int rb = wave * 16 + quad * 4;
#pragma unroll
      for (int t = 0; t < 8; t++)
#pragma unroll
        for (int r = 0; r < 4; r++)
          Cs[(rb + r) * 136 + t * 16 + l16] = f2bf(acc[t][r]);
    }
    __syncthreads();
    // epilogue (row-major, vectorized xl/xr loads)
#pragma unroll
    for (int i2 = 0; i2 < 4; i2++) {
      int r = er * 4 + i2;
      int gi = i0 + r;
      float ps = 0.f;
      if (gi < E2) {
        int s = sidx[r], d = didx[r];
#pragma unroll
        for (int h = 0; h < 2; h++) {
          int c = h * 64 + cc * 4;
          ushort4 mv = *(const ushort4*)&Cs[r * 136 + c];
          ushort4 xlu = *(const ushort4*)&xl[(size_t)s * HC + n0 + c];
          ushort4 xru = *(const ushort4*)&xr[(size_t)d * HC + n0 + c];
          float e0 = bf2f(mv.x) + bf2f(xlu.x) + bf2f(xru.x);
          float e1 = bf2f(mv.y) + bf2f(xlu.y) + bf2f(xru.y);
          float e2 = bf2f(mv.z) + bf2f(xlu.z) + bf2f(xru.z);
          float e3 = bf2f(mv.w) + bf2f(xlu.w) + bf2f(xru.w);
          e0 = e0 > 0.f ? e0 : 0.2f * e0;
          e1 = e1 > 0.f ? e1 : 0.2f * e1;
          e2 = e2 > 0.f ? e2 : 0.2f * e2;
          e3 = e3 > 0.f ? e3 : 0.2f * e3;
          ps += e0 * atts[c + 0] + e1 * atts[c + 1] + e2 * atts[c + 2] +
                e3 * atts[c + 3];
        }
      }
      ps += __shfl_xor(ps, 1);
      ps += __shfl_xor(ps, 2);
      ps += __shfl_xor(ps, 4);
      ps += __shfl_xor(ps, 8);
      if (cc == 0 && gi < E2) lg[(size_t)gi * H + head] = ps;
    }
  }
}

// ---------------------------------------------------------------------------
// attn_fused<H>: softmax + aggregate + head-mean + bias + LN + ELU.
// Wave per dst node; ext-CSR gather. xl bf16 in, hout bf16 out.
// ---------------------------------------------------------------------------
template <int H>
__global__ __launch_bounds__(256) void attn_fused(
    const unsigned short* __restrict__ xl, const float* __restrict__ lg,
    const int* __restrict__ row_ext, const int* __restrict__ ext_eid,
    const int* __restrict__ src, const float* __restrict__ bias,
    const float* __restrict__ gam, const float* __restrict__ bet,
    unsigned short* __restrict__ hout, int E, int N) {
  constexpr int HC = H * 128;
  constexpr int CPL = HC / 64;
  int lane = threadIdx.x & 63, wid = threadIdx.x >> 6;
  int n = blockIdx.x * 4 + wid;
  if (n >= N) return;
  int lo = row_ext[n], hi = row_ext[n + 1];
  int myh = (H == 2) ? (lane >> 5) : 0;
  int colbase = (H == 2) ? (myh * 128 + (lane & 31) * 4) : (lane * 2);
  float m = -3.4e38f;
  for (int j = lo; j < hi; j++) m = fmaxf(m, lg[(size_t)ext_eid[j] * H + myh]);
  float asum = 0.f;
  float acc[CPL] = {};
  for (int j = lo; j < hi; j++) {
    int e = ext_eid[j];
    int s = (e < E) ? src[e] : (e - E);
    float a = __expf(lg[(size_t)e * H + myh] - m);
    asum += a;
    const unsigned short* xp = &xl[(size_t)s * HC + colbase];
    if (H == 2) {
      ushort4 u = *(const ushort4*)xp;
      acc[0] += a * bf2f(u.x);
      acc[1] += a * bf2f(u.y);
      acc[2] += a * bf2f(u.z);
      acc[3] += a * bf2f(u.w);
    } else {
      ushort2 u = *(const ushort2*)xp;
      acc[0] += a * bf2f(u.x);
      acc[1] += a * bf2f(u.y);
    }
  }
  float inv = 1.f / fmaxf(asum, 1e-16f);
#pragma unroll
  for (int k = 0; k < CPL; k++) acc[k] *= inv;
  int ch;
  if (H == 2) {
#pragma unroll
    for (int k = 0; k < CPL; k++) acc[k] = (acc[k] + __shfl_xor(acc[k], 32)) * 0.5f;
    ch = (lane & 31) * CPL;
  } else {
    ch = lane * CPL;
  }
#pragma unroll
  for (int k = 0; k < CPL; k++) acc[k] += bias[ch + k];
  float s = 0.f;
#pragma unroll
  for (int k = 0; k < CPL; k++) s += acc[k];
#pragma unroll
  for (int mm = 1; mm < 64; mm <<= 1) s += __shfl_xor(s, mm);
  constexpr float dupn = (H == 2) ? 256.f : 128.f;
  float mu = s / dupn;
  float vs = 0.f;
#pragma unroll
  for (int k = 0; k < CPL; k++) {
    acc[k] -= mu;
    vs += acc[k] * acc[k];
  }
#pragma unroll
  for (int mm = 1; mm < 64; mm <<= 1) vs += __shfl_xor(vs, mm);
  float rstd = rsqrtf(vs / dupn + 1e-5f);
  float y[CPL];
#pragma unroll
  for (int k = 0; k < CPL; k++) {
    float v = acc[k] * rstd * gam[ch + k] + bet[ch + k];
    y[k] = v > 0.f ? v : expm1f(v);
  }
  if (H == 2) {
    if (lane < 32)
      *(ushort4*)&hout[(size_t)n * 128 + ch] =
          make_ushort4(f2bf(y[0]), f2bf(y[1]), f2bf(y[2]), f2bf(y[3]));
  } else {
    *(ushort2*)&hout[(size_t)n * 128 + ch] = make_ushort2(f2bf(y[0]), f2bf(y[1]));
  }
}

// ---------------------------------------------------------------------------
// classifier_mfma: phase1 MFMA ea@Wc -> +P[s]+Q[d]+c1b relu -> t1 (LDS bf16)
// phase2 MFMA t1@c2w -> relu,+c2b -> .c3w + c3b -> out[E].
// Wct [128][64] bf16, c2t [64][128] bf16, P/Q fp32.
// ---------------------------------------------------------------------------
__global__ __launch_bounds__(256) void classifier_mfma(
    const float* __restrict__ ea, const unsigned short* __restrict__ Wct,
    const int* __restrict__ src, const int* __restrict__ dst,
    const float* __restrict__ P, const float* __restrict__ Q,
    const float* __restrict__ c1b, const unsigned short* __restrict__ c2t,
    const float* __restrict__ c2b, const float* __restrict__ c3w,
    const float* __restrict__ c3b, float* __restrict__ out, int E) {
  __shared__ __align__(16) unsigned short asb[64 * 72];
  __shared__ __align__(16) unsigned short bsb[128 * 72];  // Wct, then c2 [64][136]
  __shared__ __align__(16) unsigned short t1s[64 * 136];
  __shared__ float c1bs[128];
  __shared__ float c2bs[64], c3ws[64];
  __shared__ int sidx[64], didx[64];
  int tid = threadIdx.x;
  int e0 = blockIdx.x * 64;
  int lane = tid & 63, wave = tid >> 6, quad = lane >> 4, l16 = lane & 15;
  if (tid < 128) c1bs[tid] = c1b[tid];
  if (tid < 64) {
    c2bs[tid] = c2b[tid];
    c3ws[tid] = c3w[tid];
    int gi = e0 + tid;
    sidx[tid] = gi < E ? src[gi] : 0;
    didx[tid] = gi < E ? dst[gi] : 0;
  }
  {  // stage A = ea rows (fp32 -> bf16)
    int row = tid & 63, kq = tid >> 6;
    int gi = e0 + row;
    if (gi < E) {
      const float* rp = ea + (size_t)gi * 64 + kq * 16;
#pragma unroll
      for (int q = 0; q < 4; q++) {
        float4 v = *(const float4*)(rp + q * 4);
        *(ushort4*)&asb[row * 72 + kq * 16 + q * 4] =
            make_ushort4(f2bf(v.x), f2bf(v.y), f2bf(v.z), f2bf(v.w));
      }
    } else {
      ushort4 z = make_ushort4(0, 0, 0, 0);
#pragma unroll
      for (int q = 0; q < 4; q++) *(ushort4*)&asb[row * 72 + kq * 16 + q * 4] = z;
    }
  }
  {  // stage Wct [128][64]
    int n = tid >> 1, hf = tid & 1;
    const ushort4* rp = (const ushort4*)(Wct + (size_t)n * 64 + hf * 32);
    ushort4* dp = (ushort4*)&bsb[n * 72 + hf * 32];
#pragma unroll
    for (int i = 0; i < 8; i++) dp[i] = rp[i];
  }
  __syncthreads();
  ffrag zero = {0.f, 0.f, 0.f, 0.f};
  int arow = wave * 16 + l16;
  {  // phase 1 MFMA
    bfrag a0 = *(const bfrag*)&asb[arow * 72 + quad * 8];
    bfrag a1 = *(const bfrag*)&asb[arow * 72 + 32 + quad * 8];
    ffrag acc[8];
#pragma unroll
    for (int t = 0; t < 8; t++) {
      acc[t] = zero;
      int bn = t * 16 + l16;
      bfrag b0 = *(const bfrag*)&bsb[bn * 72 + quad * 8];
      bfrag b1 = *(const bfrag*)&bsb[bn * 72 + 32 + quad * 8];
      acc[t] = __builtin_amdgcn_mfma_f32_16x16x32_bf16(a0, b0, acc[t], 0, 0, 0);
      acc[t] = __builtin_amdgcn_mfma_f32_16x16x32_bf16(a1, b1, acc[t], 0, 0, 0);
    }
    __syncthreads();  // bsb reads done
    int rb = wave * 16 + quad * 4;
#pragma unroll
    for (int t = 0; t < 8; t++)
#pragma unroll
      for (int r = 0; r < 4; r++)
        t1s[(rb + r) * 136 + t * 16 + l16] = f2bf(acc[t][r]);
  }
  __syncthreads();
  {  // row-major pass: t1 = relu(acc + P[s] + Q[d] + c1b); also stage c2
    int erow = tid >> 4, ccc = tid & 15;
#pragma unroll
    for (int i2 = 0; i2 < 4; i2++) {
      int r = erow * 4 + i2;
      int s = sidx[r], d = didx[r];
#pragma unroll
      for (int h = 0; h < 2; h++) {
        int c = h * 64 + ccc * 4;
        ushort4 mv = *(const ushort4*)&t1s[r * 136 + c];
        float4 pv = *(const float4*)&P[(size_t)s * 128 + c];
        float4 qv = *(const float4*)&Q[(size_t)d * 128 + c];
        float v0 = fmaxf(bf2f(mv.x) + pv.x + qv.x + c1bs[c + 0], 0.f);
        float v1 = fmaxf(bf2f(mv.y) + pv.y + qv.y + c1bs[c + 1], 0.f);
        float v2 = fmaxf(bf2f(mv.z) + pv.z + qv.z + c1bs[c + 2], 0.f);
        float v3 = fmaxf(bf2f(mv.w) + pv.w + qv.w + c1bs[c + 3], 0.f);
        *(ushort4*)&t1s[r * 136 + c] =
            make_ushort4(f2bf(v0), f2bf(v1), f2bf(v2), f2bf(v3));
      }
    }
    int n = tid >> 2, qq = tid & 3;
    const ushort4* rp = (const ushort4*)(c2t + (size_t)n * 128 + qq * 32);
    ushort4* dp = (ushort4*)&bsb[n * 136 + qq * 32];
#pragma unroll
    for (int i = 0; i < 8; i++) dp[i] = rp[i];
  }
  __syncthreads();
  {  // phase 2 MFMA: t1[64][128] @ c2[128][64]
    bfrag pa[4];
#pragma unroll
    for (int kc = 0; kc < 4; kc++)
      pa[kc] = *(const bfrag*)&t1s[arow * 136 + kc * 32 + quad * 8];
    ffrag acc2[4];
#pragma unroll
    for (int t = 0; t < 4; t++) {
      acc2[t] = zero;
      int bn = t * 16 + l16;
#pragma unroll
      for (int kc = 0; kc < 4; kc++) {
        bfrag b = *(const bfrag*)&bsb[bn * 136 + kc * 32 + quad * 8];
        acc2[t] = __builtin_amdgcn_mfma_f32_16x16x32_bf16(pa[kc], b, acc2[t], 0, 0, 0);
      }
    }
    float c3b0 = c3b[0];
    float rsum[4] = {0.f, 0.f, 0.f, 0.f};
#pragma unroll
    for (int t = 0; t < 4; t++) {
      int col = t * 16 + l16;
      float cb = c2bs[col], cw = c3ws[col];
#pragma unroll
      for (int r = 0; r < 4; r++)
        rsum[r] += fmaxf(acc2[t][r] + cb, 0.f) * cw;
    }
#pragma unroll
    for (int r = 0; r < 4; r++) {
      rsum[r] += __shfl_xor(rsum[r], 1);
      rsum[r] += __shfl_xor(rsum[r], 2);
      rsum[r] += __shfl_xor(rsum[r], 4);
      rsum[r] += __shfl_xor(rsum[r], 8);
    }
    if (l16 == 0) {
#pragma unroll
      for (int r = 0; r < 4; r++) {
        int gi = e0 + wave * 16 + quad * 4 + r;
        if (gi < E) out[gi] = rsum[r] + c3b0;
      }
    }
  }
}

// ---------------------------------------------------------------------------
extern "C" void kernel_launch(void* const* d_in, const int* in_sizes, int n_in,
                              void* d_out, int out_size, void* d_ws, size_t ws_size,
                              hipStream_t stream) {
  const int N = in_sizes[1] / 2;   // node_stats [N,2]
  const int E = in_sizes[3] / 64;  // edge_attr [E,64]
  const int E2 = E + N;

  const float* node_stats = (const float*)d_in[1];
  const int* src = (const int*)d_in[2];
  const int* dst = (const int*)d_in[2] + E;
  const float* edge_attr = (const float*)d_in[3];
  const float* epw = (const float*)d_in[4];
  const float* epb = (const float*)d_in[5];
  const float* g1wl = (const float*)d_in[6];
  const float* g1wr = (const float*)d_in[7];
  const float* g1we = (const float*)d_in[8];
  const float* g1att = (const float*)d_in[9];
  const float* g1b = (const float*)d_in[10];
  const float* n1g = (const float*)d_in[11];
  const float* n1b = (const float*)d_in[12];
  const float* g2wl = (const float*)d_in[13];
  const float* g2wr = (const float*)d_in[14];
  const float* g2we = (const float*)d_in[15];
  const float* g2att = (const float*)d_in[16];
  const float* g2b = (const float*)d_in[17];
  const float* n2g = (const float*)d_in[18];
  const float* n2b = (const float*)d_in[19];
  const float* c1w = (const float*)d_in[20];
  const float* c1b = (const float*)d_in[21];
  const float* c2w = (const float*)d_in[22];
  const float* c2b = (const float*)d_in[23];
  const float* c3w = (const float*)d_in[24];
  const float* c3b = (const float*)d_in[25];
  float* out = (float*)d_out;

  // workspace arena (float units)
  float* w = (float*)d_ws;
  size_t o = 0;
  auto alloc = [&](size_t n) { float* p = w + o; o += n; return p; };
  float* xout = alloc((size_t)N * 128);  // later P
  float* xin = alloc((size_t)N * 128);   // later Q
  float* lattr = alloc((size_t)N * 64);
  float* lg = alloc((size_t)E2 * 2);
  int* row_src = (int*)alloc((size_t)(N + 1));
  int* row_dst = (int*)alloc((size_t)(N + 1));
  int* row_ext = (int*)alloc((size_t)(N + 1));
  int* deg_src = (int*)alloc((size_t)N);  // deg pair contiguous (memset)
  int* deg_dst = (int*)alloc((size_t)N);
  int* cur_src = (int*)alloc((size_t)N);
  int* cur_ext = (int*)alloc((size_t)N);
  int* eid_src = (int*)alloc((size_t)E);
  int* ext_eid = (int*)alloc((size_t)E2);
  unsigned short* wb = (unsigned short*)alloc(140000);  // bf16 weight arena
  float* R = alloc((size_t)E * 64);  // bf16 feature arena (E*128 ushorts)
  unsigned short* Ru = (unsigned short*)R;
  unsigned short* emb = Ru;                                // E*128
  unsigned short* xl1b = Ru;                               // N*256 (emb dead)
  unsigned short* xr1b = Ru + (size_t)N * 256;             // N*256
  unsigned short* h1b = Ru + (size_t)N * 512;              // N*128
  unsigned short* xl2b = Ru + (size_t)N * 640;             // N*128
  unsigned short* xr2b = Ru + (size_t)N * 768;             // N*128
  unsigned short* h2b = Ru + (size_t)N * 896;              // N*128
  float* P = xout;
  float* Q = xin;

  // bf16 transposed weights
  unsigned short* epwt = wb + 0;        // [128][64]
  unsigned short* g1wlt = wb + 8192;    // [256][320]
  unsigned short* g1wrt = wb + 90112;   // [256][320]
  unsigned short* g1wet = wb + 172032;  // [256][64]
  unsigned short* g2wlt = wb + 188416;  // [128][128]
  unsigned short* g2wrt = wb + 204800;  // [128][128]
  unsigned short* g2wet = wb + 221184;  // [128][64]
  unsigned short* c1wat = wb + 229376;  // [128][128]
  unsigned short* c1wbt = wb + 245760;  // [128][128]
  unsigned short* c1wct = wb + 262144;  // [128][64]
  unsigned short* c2t = wb + 270336;    // [64][128]

  // ---- stage -1: weight prep (transpose + bf16) ----
  PrepJobs J;
  auto setj = [&](int i, const float* s, unsigned short* d2, int K, int Nc,
                  int KC, int ld) {
    J.src[i] = s; J.dst[i] = d2; J.K[i] = K; J.Nc[i] = Nc; J.KC[i] = KC; J.ld[i] = ld;
  };
  setj(0, epw, epwt, 64, 128, 64, 128);
  setj(1, g1wl, g1wlt, 258, 256, 320, 256);
  setj(2, g1wr, g1wrt, 258, 256, 320, 256);
  setj(3, g1we, g1wet, 64, 256, 64, 256);
  setj(4, g2wl, g2wlt, 128, 128, 128, 128);
  setj(5, g2wr, g2wrt, 128, 128, 128, 128);
  setj(6, g2we, g2wet, 64, 128, 64, 128);
  setj(7, c1w, c1wat, 128, 128, 128, 128);
  setj(8, c1w + 128 * 128, c1wbt, 128, 128, 128, 128);
  setj(9, c1w + 256 * 128, c1wct, 64, 128, 64, 128);
  setj(10, c2w, c2t, 128, 64, 128, 64);
  prep_bt<<<dim3(11, 32), 256, 0, stream>>>(J);

  // ---- stage 0: CSR (src) + extended dst CSR ----
  hipMemsetAsync(deg_src, 0, (size_t)2 * N * sizeof(int), stream);
  count_deg<<<cdiv(E, 256), 256, 0, stream>>>(src, dst, deg_src, deg_dst, E);
  scan_pair<<<1, 1024, 0, stream>>>(deg_src, deg_dst, row_src, row_dst, cur_src,
                                    cur_ext, N);
  ext_fix<<<cdiv(N + 1, 256), 256, 0, stream>>>(row_dst, row_ext, cur_ext,
                                                ext_eid, E, N);
  scatter_eid<<<cdiv(E, 256), 256, 0, stream>>>(src, dst, cur_src, cur_ext,
                                                eid_src, ext_eid, E);

  ASrc dummy{nullptr, nullptr, nullptr, 0, 0, 0, 0, 0};

  // ---- stage 1: emb = relu(ea@epw+epb) bf16; gather means ----
  {
    ASrc a{edge_attr, nullptr, nullptr, 64, 0, 0, 64, 64};
    gemm_mfma<1, 1, 0><<<dim3(cdiv(E, 64), 1), 256, 0, stream>>>(
        a, nullptr, 0, epwt, 64, epb, emb, 128, E, 64);
  }
  gather_mean<<<dim3(cdiv(N, 4), 2), 256, 0, stream>>>(
      row_src, eid_src, row_ext, ext_eid, emb, edge_attr, xout, xin, lattr, N);

  // ---- stage 2: xl1/xr1 (bf16) = xi @ g1wl / g1wr (K=258, Nc=256) ----
  {
    ASrc a{xout, xin, node_stats, 128, 128, 2, 128, 256};
    dim3 g(cdiv(N, 64), 2);
    gemm_mfma<0, 1, 0><<<g, 256, 0, stream>>>(a, nullptr, 0, g1wlt, 320, nullptr,
                                              xl1b, 256, N, 258);
    gemm_mfma<0, 1, 0><<<g, 256, 0, stream>>>(a, nullptr, 0, g1wrt, 320, nullptr,
                                              xr1b, 256, N, 258);
  }

  // ---- stage 3: GATv2 layer 1 (H=2) ----
  attn_logits_mfma<2><<<cdiv(E2, 64), 256, 0, stream>>>(
      xl1b, xr1b, src, dst, edge_attr, lattr, g1wet, g1att, lg, E, N);
  attn_fused<2><<<cdiv(N, 4), 256, 0, stream>>>(xl1b, lg, row_ext, ext_eid, src,
                                                g1b, n1g, n1b, h1b, E, N);

  // ---- stage 4: xl2/xr2 (bf16) = h1 @ g2wl / g2wr ----
  {
    dim3 g(cdiv(N, 64), 1);
    gemm_mfma<0, 1, 1><<<g, 256, 0, stream>>>(dummy, h1b, 128, g2wlt, 128,
                                              nullptr, xl2b, 128, N, 128);
    gemm_mfma<0, 1, 1><<<g, 256, 0, stream>>>(dummy, h1b, 128, g2wrt, 128,
                                              nullptr, xr2b, 128, N, 128);
  }

  // ---- stage 5: GATv2 layer 2 (H=1) ----
  attn_logits_mfma<1><<<cdiv(E2, 64), 256, 0, stream>>>(
      xl2b, xr2b, src, dst, edge_attr, lattr, g2wet, g2att, lg, E, N);
  attn_fused<1><<<cdiv(N, 4), 256, 0, stream>>>(xl2b, lg, row_ext, ext_eid, src,
                                                g2b, n2g, n2b, h2b, E, N);

  // ---- stage 6: classifier ----
  {
    dim3 g(cdiv(N, 64), 1);
    gemm_mfma<0, 0, 1><<<g, 256, 0, stream>>>(dummy, h2b, 128, c1wat, 128,
                                              nullptr, P, 128, N, 128);
    gemm_mfma<0, 0, 1><<<g, 256, 0, stream>>>(dummy, h2b, 128, c1wbt, 128,
                                              nullptr, Q, 128, N, 128);
  }
  classifier_mfma<<<cdiv(E, 64), 256, 0, stream>>>(
      edge_attr, c1wct, src, dst, P, Q, c1b, c2t, c2b, c3w, c3b, out, E);
}

// Round 7
// 1068.660 us; speedup vs baseline: 1.8794x; 1.1869x over previous
//
#include <hip/hip_runtime.h>
#include <cstdint>
#include <cstddef>

// ---------------------------------------------------------------------------
// StaticGNN fused pipeline, round 7: parallel 3-phase CSR scan (kills the
// 220us single-block scan) + round-6 MFMA pipeline.
// N=50000, E=400000, ND=128, ED=64, HID=128.
// ---------------------------------------------------------------------------

static inline int cdiv(int a, int b) { return (a + b - 1) / b; }

typedef __attribute__((ext_vector_type(8))) short bfrag;   // 8 bf16 (4 VGPRs)
typedef __attribute__((ext_vector_type(4))) float ffrag;   // 4 fp32 acc

__device__ __forceinline__ float bf2f(unsigned short u) {
  return __uint_as_float(((unsigned)u) << 16);
}
__device__ __forceinline__ unsigned short f2bf(float f) {
  unsigned b = __float_as_uint(f);
  return (unsigned short)((b + 0x7FFFu + ((b >> 16) & 1u)) >> 16);
}

// ---------------------------------------------------------------------------
// Weight prep: W[K][Nc] fp32 -> Wt[Nc][KC] bf16 (zero-padded K -> KC).
// ---------------------------------------------------------------------------
struct PrepJobs {
  const float* src[11];
  unsigned short* dst[11];
  int K[11], Nc[11], KC[11], ld[11];
};
__global__ void prep_bt(PrepJobs J) {
  int j = blockIdx.x;
  int K = J.K[j], Nc = J.Nc[j], KC = J.KC[j], ld = J.ld[j];
  const float* S = J.src[j];
  unsigned short* D = J.dst[j];
  for (int n = blockIdx.y; n < Nc; n += gridDim.y)
    for (int t = threadIdx.x; t < KC; t += blockDim.x) {
      float v = (t < K) ? S[(size_t)t * ld + n] : 0.f;
      D[(size_t)n * KC + t] = f2bf(v);
    }
}

// ---------------------------------------------------------------------------
// CSR build: degree count, 3-phase parallel exclusive scan, slot scatter.
// ---------------------------------------------------------------------------
__global__ void count_deg(const int* __restrict__ src, const int* __restrict__ dst,
                          int* __restrict__ dsrc, int* __restrict__ ddst, int E) {
  int t = blockIdx.x * blockDim.x + threadIdx.x;
  if (t < E) {
    atomicAdd(&dsrc[src[t]], 1);
    atomicAdd(&ddst[dst[t]], 1);
  }
}

// phase 1: per-block exclusive scan, block totals to bsum[arr*nb + b]
__global__ __launch_bounds__(256) void scan_local(
    const int* __restrict__ degA, const int* __restrict__ degB,
    int* __restrict__ rowA, int* __restrict__ rowB, int* __restrict__ bsum,
    int N, int nb) {
  __shared__ int s[256];
  int arr = blockIdx.y;
  const int* deg = arr ? degB : degA;
  int* row = arr ? rowB : rowA;
  int b = blockIdx.x;
  int i = b * 256 + threadIdx.x;
  int v = (i < N) ? deg[i] : 0;
  s[threadIdx.x] = v;
  __syncthreads();
  for (int off = 1; off < 256; off <<= 1) {
    int t = (threadIdx.x >= off) ? s[threadIdx.x - off] : 0;
    __syncthreads();
    s[threadIdx.x] += t;
    __syncthreads();
  }
  int incl = s[threadIdx.x];
  if (i < N) row[i] = incl - v;
  if (threadIdx.x == 255) bsum[arr * nb + b] = incl;
}

// phase 2: single block scans both bsum arrays (nb <= 1024), writes row[N]
__global__ __launch_bounds__(1024) void scan_bsums(int* __restrict__ bsum, int nb,
                                                   int* __restrict__ rowA,
                                                   int* __restrict__ rowB, int N) {
  __shared__ int s[1024];
  int tid = threadIdx.x;
  for (int arr = 0; arr < 2; arr++) {
    int v = (tid < nb) ? bsum[arr * nb + tid] : 0;
    s[tid] = v;
    __syncthreads();
    for (int off = 1; off < 1024; off <<= 1) {
      int t = (tid >= off) ? s[tid - off] : 0;
      __syncthreads();
      s[tid] += t;
      __syncthreads();
    }
    if (tid < nb) bsum[arr * nb + tid] = s[tid] - v;
    if (tid == nb - 1) {
      int* row = arr ? rowB : rowA;
      row[N] = s[tid];
    }
    __syncthreads();
  }
}

// phase 3: add block offsets; emit cur_src for the src side
__global__ void scan_add(int* __restrict__ rowA, int* __restrict__ rowB,
                         int* __restrict__ curA, const int* __restrict__ bsum,
                         int N, int nb) {
  int arr = blockIdx.y;
  int* row = arr ? rowB : rowA;
  int b = blockIdx.x;
  int i = b * 256 + threadIdx.x;
  if (i < N) {
    int v = row[i] + bsum[arr * nb + b];
    row[i] = v;
    if (arr == 0) curA[i] = v;
  }
}

__global__ void ext_fix(const int* __restrict__ row_dst, int* __restrict__ row_ext,
                        int* __restrict__ cur_ext, int* __restrict__ ext_eid,
                        int E, int N) {
  int i = blockIdx.x * blockDim.x + threadIdx.x;
  if (i <= N) row_ext[i] = row_dst[i] + i;
  if (i < N) {
    cur_ext[i] = row_dst[i] + i;
    ext_eid[row_dst[i + 1] + i] = E + i;
  }
}

__global__ void scatter_eid(const int* __restrict__ src, const int* __restrict__ dst,
                            int* __restrict__ csrc, int* __restrict__ cext,
                            int* __restrict__ esrc, int* __restrict__ ext_eid,
                            int E) {
  int t = blockIdx.x * blockDim.x + threadIdx.x;
  if (t < E) {
    int p = atomicAdd(&csrc[src[t]], 1);
    esrc[p] = t;
    int q = atomicAdd(&cext[dst[t]], 1);
    ext_eid[q] = t;
  }
}

// ---------------------------------------------------------------------------
// Virtual 3-way concatenated A operand (fp32 sources).
// ---------------------------------------------------------------------------
struct ASrc {
  const float *p0, *p1, *p2;
  int ld0, ld1, ld2, k0, k1;
};
__device__ __forceinline__ float loadA(const ASrc& a, int m, int k) {
  if (k < a.k0) return a.p0[(size_t)m * a.ld0 + k];
  if (k < a.k1) return a.p1[(size_t)m * a.ld1 + (k - a.k0)];
  return a.p2[(size_t)m * a.ld2 + (k - a.k1)];
}
__device__ __forceinline__ int regionOf(const ASrc& a, int k) {
  return k < a.k0 ? 0 : (k < a.k1 ? 1 : 2);
}

// ---------------------------------------------------------------------------
// MFMA GEMM: C[M, n0..n0+128) = act(A[M,K] @ B + bias). 64x128 tile, 4 waves.
// ---------------------------------------------------------------------------
template <int ACT, int OBF, int ABF>
__global__ __launch_bounds__(256) void gemm_mfma(
    ASrc A, const unsigned short* __restrict__ Abf, int lda,
    const unsigned short* __restrict__ Bt, int ldbt,
    const float* __restrict__ bias, void* __restrict__ Cv, int ldc, int M, int K) {
  __shared__ __align__(16) unsigned short asb[64 * 72];
  __shared__ __align__(16) unsigned short bsb[128 * 72];
  int tid = threadIdx.x;
  int m0 = blockIdx.x * 64, n0 = blockIdx.y * 128;
  int lane = tid & 63, wave = tid >> 6;
  int quad = lane >> 4, l16 = lane & 15;
  ffrag zero = {0.f, 0.f, 0.f, 0.f};
  ffrag acc[8];
#pragma unroll
  for (int t = 0; t < 8; t++) acc[t] = zero;
  int KC = (K + 63) & ~63;
  for (int kc = 0; kc < KC; kc += 64) {
    __syncthreads();
    {  // stage A -> bf16 LDS [64][72]
      int row = tid & 63, kq = tid >> 6;
      int gm = m0 + row;
      if (ABF) {
        const unsigned short* rp = Abf + (size_t)gm * lda + kc + kq * 16;
        ushort4 z = make_ushort4(0, 0, 0, 0);
#pragma unroll
        for (int q = 0; q < 4; q++) {
          ushort4 v = (gm < M) ? *(const ushort4*)(rp + q * 4) : z;
          *(ushort4*)&asb[row * 72 + kq * 16 + q * 4] = v;
        }
      } else {
        bool fastc = (kc + 64 <= K) && (regionOf(A, kc) == regionOf(A, kc + 63)) &&
                     (gm < M);
        if (fastc) {
          int r = regionOf(A, kc);
          const float* p;
          int ld, koff;
          if (r == 0) { p = A.p0; ld = A.ld0; koff = 0; }
          else if (r == 1) { p = A.p1; ld = A.ld1; koff = A.k0; }
          else { p = A.p2; ld = A.ld2; koff = A.k1; }
          const float* rp = p + (size_t)gm * ld + (kc - koff) + kq * 16;
#pragma unroll
          for (int q = 0; q < 4; q++) {
            float4 v = *(const float4*)(rp + q * 4);
            *(ushort4*)&asb[row * 72 + kq * 16 + q * 4] =
                make_ushort4(f2bf(v.x), f2bf(v.y), f2bf(v.z), f2bf(v.w));
          }
        } else {
#pragma unroll
          for (int q = 0; q < 16; q++) {
            int kk = kc + kq * 16 + q;
            float v = (gm < M && kk < K) ? loadA(A, gm, kk) : 0.f;
            asb[row * 72 + kq * 16 + q] = f2bf(v);
          }
        }
      }
    }
    {  // stage B chunk
      int n = tid >> 1, hf = tid & 1;
      const ushort4* rp = (const ushort4*)(Bt + (size_t)(n0 + n) * ldbt + kc + hf * 32);
      ushort4* dp = (ushort4*)&bsb[n * 72 + hf * 32];
#pragma unroll
      for (int i = 0; i < 8; i++) dp[i] = rp[i];
    }
    __syncthreads();
    int arow = wave * 16 + l16;
    bfrag a0 = *(const bfrag*)&asb[arow * 72 + quad * 8];
    bfrag a1 = *(const bfrag*)&asb[arow * 72 + 32 + quad * 8];
#pragma unroll
    for (int t = 0; t < 8; t++) {
      int bn = t * 16 + l16;
      bfrag b0 = *(const bfrag*)&bsb[bn * 72 + quad * 8];
      bfrag b1 = *(const bfrag*)&bsb[bn * 72 + 32 + quad * 8];
      acc[t] = __builtin_amdgcn_mfma_f32_16x16x32_bf16(a0, b0, acc[t], 0, 0, 0);
      acc[t] = __builtin_amdgcn_mfma_f32_16x16x32_bf16(a1, b1, acc[t], 0, 0, 0);
    }
  }
#pragma unroll
  for (int t = 0; t < 8; t++) {
    int col = n0 + t * 16 + l16;
    float bv = bias ? bias[col] : 0.f;
#pragma unroll
    for (int r = 0; r < 4; r++) {
      int row = m0 + wave * 16 + quad * 4 + r;
      if (row < M) {
        float v = acc[t][r] + bv;
        if (ACT == 1) v = fmaxf(v, 0.f);
        if (OBF)
          ((unsigned short*)Cv)[(size_t)row * ldc + col] = f2bf(v);
        else
          ((float*)Cv)[(size_t)row * ldc + col] = v;
      }
    }
  }
}

// ---------------------------------------------------------------------------
// gather-mean (emb bf16)
// ---------------------------------------------------------------------------
__global__ __launch_bounds__(256) void gather_mean(
    const int* __restrict__ row_src, const int* __restrict__ eid_src,
    const int* __restrict__ row_ext, const int* __restrict__ ext_eid,
    const unsigned short* __restrict__ emb, const float* __restrict__ ea,
    float* __restrict__ xout, float* __restrict__ xin, float* __restrict__ lattr,
    int N) {
  int lane = threadIdx.x & 63, wid = threadIdx.x >> 6;
  int n = blockIdx.x * 4 + wid;
  int side = blockIdx.y;
  if (n >= N) return;
  int lo, hi;
  const int* eid;
  if (side) { lo = row_ext[n]; hi = row_ext[n + 1] - 1; eid = ext_eid; }
  else { lo = row_src[n]; hi = row_src[n + 1]; eid = eid_src; }
  float a0 = 0.f, a1 = 0.f, la = 0.f;
  for (int j = lo; j < hi; j++) {
    int e = eid[j];
    ushort2 v = *(const ushort2*)&emb[(size_t)e * 128 + lane * 2];
    a0 += bf2f(v.x);
    a1 += bf2f(v.y);
    if (side) la += ea[(size_t)e * 64 + lane];
  }
  float r = 1.f / fmaxf((float)(hi - lo), 1.f);
  float* ob = side ? xin : xout;
  *(float2*)&ob[(size_t)n * 128 + lane * 2] = make_float2(a0 * r, a1 * r);
  if (side) lattr[(size_t)n * 64 + lane] = la * r;
}

// ---------------------------------------------------------------------------
// attn_logits_mfma<H>
// ---------------------------------------------------------------------------
template <int H>
__global__ __launch_bounds__(256) void attn_logits_mfma(
    const unsigned short* __restrict__ xl, const unsigned short* __restrict__ xr,
    const int* __restrict__ src, const int* __restrict__ dst,
    const float* __restrict__ ea, const float* __restrict__ lattr,
    const unsigned short* __restrict__ wet, const float* __restrict__ att,
    float* __restrict__ lg, int E, int N) {
  constexpr int HC = H * 128;
  __shared__ __align__(16) unsigned short asb[64 * 72];
  __shared__ __align__(16) unsigned short bsb[128 * 72];  // reused as Cs[64][136]
  __shared__ float atts[128];
  __shared__ int sidx[64], didx[64];
  unsigned short* Cs = bsb;
  int tid = threadIdx.x;
  int E2 = E + N;
  int i0 = blockIdx.x * 64;
  int lane = tid & 63, wave = tid >> 6, quad = lane >> 4, l16 = lane & 15;
  if (tid < 64) {
    int gi = i0 + tid;
    int s = 0, d = 0;
    if (gi < E2) {
      if (gi < E) { s = src[gi]; d = dst[gi]; }
      else { s = d = gi - E; }
    }
    sidx[tid] = s;
    didx[tid] = d;
  }
  {  // stage A once
    int row = tid & 63, kq = tid >> 6;
    int gi = i0 + row;
    if (gi < E2) {
      const float* ap =
          (gi < E) ? ea + (size_t)gi * 64 : lattr + (size_t)(gi - E) * 64;
      const float* rp = ap + kq * 16;
#pragma unroll
      for (int q = 0; q < 4; q++) {
        float4 v = *(const float4*)(rp + q * 4);
        *(ushort4*)&asb[row * 72 + kq * 16 + q * 4] =
            make_ushort4(f2bf(v.x), f2bf(v.y), f2bf(v.z), f2bf(v.w));
      }
    } else {
      ushort4 z = make_ushort4(0, 0, 0, 0);
#pragma unroll
      for (int q = 0; q < 4; q++) *(ushort4*)&asb[row * 72 + kq * 16 + q * 4] = z;
    }
  }
  int er = tid >> 4, cc = tid & 15;
  ffrag zero = {0.f, 0.f, 0.f, 0.f};
  for (int head = 0; head < H; head++) {
    int n0 = head * 128;
    __syncthreads();
    if (tid < 128) atts[tid] = att[n0 + tid];
    {
      int n = tid >> 1, hf = tid & 1;
      const ushort4* rp = (const ushort4*)(wet + (size_t)(n0 + n) * 64 + hf * 32);
      ushort4* dp = (ushort4*)&bsb[n * 72 + hf * 32];
#pragma unroll
      for (int i = 0; i < 8; i++) dp[i] = rp[i];
    }
    __syncthreads();
    int arow = wave * 16 + l16;
    bfrag a0 = *(const bfrag*)&asb[arow * 72 + quad * 8];
    bfrag a1 = *(const bfrag*)&asb[arow * 72 + 32 + quad * 8];
    ffrag acc[8];
#pragma unroll
    for (int t = 0; t < 8; t++) {
      acc[t] = zero;
      int bn = t * 16 + l16;
      bfrag b0 = *(const bfrag*)&bsb[bn * 72 + quad * 8];
      bfrag b1 = *(const bfrag*)&bsb[bn * 72 + 32 + quad * 8];
      acc[t] = __builtin_amdgcn_mfma_f32_16x16x32_bf16(a0, b0, acc[t], 0, 0, 0);
      acc[t] = __builtin_amdgcn_mfma_f32_16x16x32_bf16(a1, b1, acc[t], 0, 0, 0);
    }
    __syncthreads();
    {
      int rb = wave * 16 + quad * 4;
#pragma unroll
      for (int t = 0; t < 8; t++)
#pragma unroll
        for (int r = 0; r < 4; r++)
          Cs[(rb + r) * 136 + t * 16 + l16] = f2bf(acc[t][r]);
    }
    __syncthreads();
#pragma unroll
    for (int i2 = 0; i2 < 4; i2++) {
      int r = er * 4 + i2;
      int gi = i0 + r;
      float ps = 0.f;
      if (gi < E2) {
        int s = sidx[r], d = didx[r];
#pragma unroll
        for (int h = 0; h < 2; h++) {
          int c = h * 64 + cc * 4;
          ushort4 mv = *(const ushort4*)&Cs[r * 136 + c];
          ushort4 xlu = *(const ushort4*)&xl[(size_t)s * HC + n0 + c];
          ushort4 xru = *(const ushort4*)&xr[(size_t)d * HC + n0 + c];
          float e0 = bf2f(mv.x) + bf2f(xlu.x) + bf2f(xru.x);
          float e1 = bf2f(mv.y) + bf2f(xlu.y) + bf2f(xru.y);
          float e2 = bf2f(mv.z) + bf2f(xlu.z) + bf2f(xru.z);
          float e3 = bf2f(mv.w) + bf2f(xlu.w) + bf2f(xru.w);
          e0 = e0 > 0.f ? e0 : 0.2f * e0;
          e1 = e1 > 0.f ? e1 : 0.2f * e1;
          e2 = e2 > 0.f ? e2 : 0.2f * e2;
          e3 = e3 > 0.f ? e3 : 0.2f * e3;
          ps += e0 * atts[c + 0] + e1 * atts[c + 1] + e2 * atts[c + 2] +
                e3 * atts[c + 3];
        }
      }
      ps += __shfl_xor(ps, 1);
      ps += __shfl_xor(ps, 2);
      ps += __shfl_xor(ps, 4);
      ps += __shfl_xor(ps, 8);
      if (cc == 0 && gi < E2) lg[(size_t)gi * H + head] = ps;
    }
  }
}

// ---------------------------------------------------------------------------
// attn_fused<H>
// ---------------------------------------------------------------------------
template <int H>
__global__ __launch_bounds__(256) void attn_fused(
    const unsigned short* __restrict__ xl, const float* __restrict__ lg,
    const int* __restrict__ row_ext, const int* __restrict__ ext_eid,
    const int* __restrict__ src, const float* __restrict__ bias,
    const float* __restrict__ gam, const float* __restrict__ bet,
    unsigned short* __restrict__ hout, int E, int N) {
  constexpr int HC = H * 128;
  constexpr int CPL = HC / 64;
  int lane = threadIdx.x & 63, wid = threadIdx.x >> 6;
  int n = blockIdx.x * 4 + wid;
  if (n >= N) return;
  int lo = row_ext[n], hi = row_ext[n + 1];
  int myh = (H == 2) ? (lane >> 5) : 0;
  int colbase = (H == 2) ? (myh * 128 + (lane & 31) * 4) : (lane * 2);
  float m = -3.4e38f;
  for (int j = lo; j < hi; j++) m = fmaxf(m, lg[(size_t)ext_eid[j] * H + myh]);
  float asum = 0.f;
  float acc[CPL] = {};
  for (int j = lo; j < hi; j++) {
    int e = ext_eid[j];
    int s = (e < E) ? src[e] : (e - E);
    float a = __expf(lg[(size_t)e * H + myh] - m);
    asum += a;
    const unsigned short* xp = &xl[(size_t)s * HC + colbase];
    if (H == 2) {
      ushort4 u = *(const ushort4*)xp;
      acc[0] += a * bf2f(u.x);
      acc[1] += a * bf2f(u.y);
      acc[2] += a * bf2f(u.z);
      acc[3] += a * bf2f(u.w);
    } else {
      ushort2 u = *(const ushort2*)xp;
      acc[0] += a * bf2f(u.x);
      acc[1] += a * bf2f(u.y);
    }
  }
  float inv = 1.f / fmaxf(asum, 1e-16f);
#pragma unroll
  for (int k = 0; k < CPL; k++) acc[k] *= inv;
  int ch;
  if (H == 2) {
#pragma unroll
    for (int k = 0; k < CPL; k++) acc[k] = (acc[k] + __shfl_xor(acc[k], 32)) * 0.5f;
    ch = (lane & 31) * CPL;
  } else {
    ch = lane * CPL;
  }
#pragma unroll
  for (int k = 0; k < CPL; k++) acc[k] += bias[ch + k];
  float s = 0.f;
#pragma unroll
  for (int k = 0; k < CPL; k++) s += acc[k];
#pragma unroll
  for (int mm = 1; mm < 64; mm <<= 1) s += __shfl_xor(s, mm);
  constexpr float dupn = (H == 2) ? 256.f : 128.f;
  float mu = s / dupn;
  float vs = 0.f;
#pragma unroll
  for (int k = 0; k < CPL; k++) {
    acc[k] -= mu;
    vs += acc[k] * acc[k];
  }
#pragma unroll
  for (int mm = 1; mm < 64; mm <<= 1) vs += __shfl_xor(vs, mm);
  float rstd = rsqrtf(vs / dupn + 1e-5f);
  float y[CPL];
#pragma unroll
  for (int k = 0; k < CPL; k++) {
    float v = acc[k] * rstd * gam[ch + k] + bet[ch + k];
    y[k] = v > 0.f ? v : expm1f(v);
  }
  if (H == 2) {
    if (lane < 32)
      *(ushort4*)&hout[(size_t)n * 128 + ch] =
          make_ushort4(f2bf(y[0]), f2bf(y[1]), f2bf(y[2]), f2bf(y[3]));
  } else {
    *(ushort2*)&hout[(size_t)n * 128 + ch] = make_ushort2(f2bf(y[0]), f2bf(y[1]));
  }
}

// ---------------------------------------------------------------------------
// classifier_mfma
// ---------------------------------------------------------------------------
__global__ __launch_bounds__(256) void classifier_mfma(
    const float* __restrict__ ea, const unsigned short* __restrict__ Wct,
    const int* __restrict__ src, const int* __restrict__ dst,
    const float* __restrict__ P, const float* __restrict__ Q,
    const float* __restrict__ c1b, const unsigned short* __restrict__ c2t,
    const float* __restrict__ c2b, const float* __restrict__ c3w,
    const float* __restrict__ c3b, float* __restrict__ out, int E) {
  __shared__ __align__(16) unsigned short asb[64 * 72];
  __shared__ __align__(16) unsigned short bsb[128 * 72];
  __shared__ __align__(16) unsigned short t1s[64 * 136];
  __shared__ float c1bs[128];
  __shared__ float c2bs[64], c3ws[64];
  __shared__ int sidx[64], didx[64];
  int tid = threadIdx.x;
  int e0 = blockIdx.x * 64;
  int lane = tid & 63, wave = tid >> 6, quad = lane >> 4, l16 = lane & 15;
  if (tid < 128) c1bs[tid] = c1b[tid];
  if (tid < 64) {
    c2bs[tid] = c2b[tid];
    c3ws[tid] = c3w[tid];
    int gi = e0 + tid;
    sidx[tid] = gi < E ? src[gi] : 0;
    didx[tid] = gi < E ? dst[gi] : 0;
  }
  {
    int row = tid & 63, kq = tid >> 6;
    int gi = e0 + row;
    if (gi < E) {
      const float* rp = ea + (size_t)gi * 64 + kq * 16;
#pragma unroll
      for (int q = 0; q < 4; q++) {
        float4 v = *(const float4*)(rp + q * 4);
        *(ushort4*)&asb[row * 72 + kq * 16 + q * 4] =
            make_ushort4(f2bf(v.x), f2bf(v.y), f2bf(v.z), f2bf(v.w));
      }
    } else {
      ushort4 z = make_ushort4(0, 0, 0, 0);
#pragma unroll
      for (int q = 0; q < 4; q++) *(ushort4*)&asb[row * 72 + kq * 16 + q * 4] = z;
    }
  }
  {
    int n = tid >> 1, hf = tid & 1;
    const ushort4* rp = (const ushort4*)(Wct + (size_t)n * 64 + hf * 32);
    ushort4* dp = (ushort4*)&bsb[n * 72 + hf * 32];
#pragma unroll
    for (int i = 0; i < 8; i++) dp[i] = rp[i];
  }
  __syncthreads();
  ffrag zero = {0.f, 0.f, 0.f, 0.f};
  int arow = wave * 16 + l16;
  {
    bfrag a0 = *(const bfrag*)&asb[arow * 72 + quad * 8];
    bfrag a1 = *(const bfrag*)&asb[arow * 72 + 32 + quad * 8];
    ffrag acc[8];
#pragma unroll
    for (int t = 0; t < 8; t++) {
      acc[t] = zero;
      int bn = t * 16 + l16;
      bfrag b0 = *(const bfrag*)&bsb[bn * 72 + quad * 8];
      bfrag b1 = *(const bfrag*)&bsb[bn * 72 + 32 + quad * 8];
      acc[t] = __builtin_amdgcn_mfma_f32_16x16x32_bf16(a0, b0, acc[t], 0, 0, 0);
      acc[t] = __builtin_amdgcn_mfma_f32_16x16x32_bf16(a1, b1, acc[t], 0, 0, 0);
    }
    __syncthreads();
    int rb = wave * 16 + quad * 4;
#pragma unroll
    for (int t = 0; t < 8; t++)
#pragma unroll
      for (int r = 0; r < 4; r++)
        t1s[(rb + r) * 136 + t * 16 + l16] = f2bf(acc[t][r]);
  }
  __syncthreads();
  {
    int erow = tid >> 4, ccc = tid & 15;
#pragma unroll
    for (int i2 = 0; i2 < 4; i2++) {
      int r = erow * 4 + i2;
      int s = sidx[r], d = didx[r];
#pragma unroll
      for (int h = 0; h < 2; h++) {
        int c = h * 64 + ccc * 4;
        ushort4 mv = *(const ushort4*)&t1s[r * 136 + c];
        float4 pv = *(const float4*)&P[(size_t)s * 128 + c];
        float4 qv = *(const float4*)&Q[(size_t)d * 128 + c];
        float v0 = fmaxf(bf2f(mv.x) + pv.x + qv.x + c1bs[c + 0], 0.f);
        float v1 = fmaxf(bf2f(mv.y) + pv.y + qv.y + c1bs[c + 1], 0.f);
        float v2 = fmaxf(bf2f(mv.z) + pv.z + qv.z + c1bs[c + 2], 0.f);
        float v3 = fmaxf(bf2f(mv.w) + pv.w + qv.w + c1bs[c + 3], 0.f);
        *(ushort4*)&t1s[r * 136 + c] =
            make_ushort4(f2bf(v0), f2bf(v1), f2bf(v2), f2bf(v3));
      }
    }
    int n = tid >> 2, qq = tid & 3;
    const ushort4* rp = (const ushort4*)(c2t + (size_t)n * 128 + qq * 32);
    ushort4* dp = (ushort4*)&bsb[n * 136 + qq * 32];
#pragma unroll
    for (int i = 0; i < 8; i++) dp[i] = rp[i];
  }
  __syncthreads();
  {
    bfrag pa[4];
#pragma unroll
    for (int kc = 0; kc < 4; kc++)
      pa[kc] = *(const bfrag*)&t1s[arow * 136 + kc * 32 + quad * 8];
    ffrag acc2[4];
#pragma unroll
    for (int t = 0; t < 4; t++) {
      acc2[t] = zero;
      int bn = t * 16 + l16;
#pragma unroll
      for (int kc = 0; kc < 4; kc++) {
        bfrag b = *(const bfrag*)&bsb[bn * 136 + kc * 32 + quad * 8];
        acc2[t] = __builtin_amdgcn_mfma_f32_16x16x32_bf16(pa[kc], b, acc2[t], 0, 0, 0);
      }
    }
    float c3b0 = c3b[0];
    float rsum[4] = {0.f, 0.f, 0.f, 0.f};
#pragma unroll
    for (int t = 0; t < 4; t++) {
      int col = t * 16 + l16;
      float cb = c2bs[col], cw = c3ws[col];
#pragma unroll
      for (int r = 0; r < 4; r++)
        rsum[r] += fmaxf(acc2[t][r] + cb, 0.f) * cw;
    }
#pragma unroll
    for (int r = 0; r < 4; r++) {
      rsum[r] += __shfl_xor(rsum[r], 1);
      rsum[r] += __shfl_xor(rsum[r], 2);
      rsum[r] += __shfl_xor(rsum[r], 4);
      rsum[r] += __shfl_xor(rsum[r], 8);
    }
    if (l16 == 0) {
#pragma unroll
      for (int r = 0; r < 4; r++) {
        int gi = e0 + wave * 16 + quad * 4 + r;
        if (gi < E) out[gi] = rsum[r] + c3b0;
      }
    }
  }
}

// ---------------------------------------------------------------------------
extern "C" void kernel_launch(void* const* d_in, const int* in_sizes, int n_in,
                              void* d_out, int out_size, void* d_ws, size_t ws_size,
                              hipStream_t stream) {
  const int N = in_sizes[1] / 2;   // node_stats [N,2]
  const int E = in_sizes[3] / 64;  // edge_attr [E,64]
  const int E2 = E + N;
  const int nb = cdiv(N, 256);     // scan blocks per array (<=1024)

  const float* node_stats = (const float*)d_in[1];
  const int* src = (const int*)d_in[2];
  const int* dst = (const int*)d_in[2] + E;
  const float* edge_attr = (const float*)d_in[3];
  const float* epw = (const float*)d_in[4];
  const float* epb = (const float*)d_in[5];
  const float* g1wl = (const float*)d_in[6];
  const float* g1wr = (const float*)d_in[7];
  const float* g1we = (const float*)d_in[8];
  const float* g1att = (const float*)d_in[9];
  const float* g1b = (const float*)d_in[10];
  const float* n1g = (const float*)d_in[11];
  const float* n1b = (const float*)d_in[12];
  const float* g2wl = (const float*)d_in[13];
  const float* g2wr = (const float*)d_in[14];
  const float* g2we = (const float*)d_in[15];
  const float* g2att = (const float*)d_in[16];
  const float* g2b = (const float*)d_in[17];
  const float* n2g = (const float*)d_in[18];
  const float* n2b = (const float*)d_in[19];
  const float* c1w = (const float*)d_in[20];
  const float* c1b = (const float*)d_in[21];
  const float* c2w = (const float*)d_in[22];
  const float* c2b = (const float*)d_in[23];
  const float* c3w = (const float*)d_in[24];
  const float* c3b = (const float*)d_in[25];
  float* out = (float*)d_out;

  // workspace arena (float units)
  float* w = (float*)d_ws;
  size_t o = 0;
  auto alloc = [&](size_t n) { float* p = w + o; o += n; return p; };
  float* xout = alloc((size_t)N * 128);  // later P
  float* xin = alloc((size_t)N * 128);   // later Q
  float* lattr = alloc((size_t)N * 64);
  float* lg = alloc((size_t)E2 * 2);
  int* row_src = (int*)alloc((size_t)(N + 1));
  int* row_dst = (int*)alloc((size_t)(N + 1));
  int* row_ext = (int*)alloc((size_t)(N + 1));
  int* deg_src = (int*)alloc((size_t)N);  // deg pair contiguous (memset)
  int* deg_dst = (int*)alloc((size_t)N);
  int* cur_src = (int*)alloc((size_t)N);
  int* cur_ext = (int*)alloc((size_t)N);
  int* eid_src = (int*)alloc((size_t)E);
  int* ext_eid = (int*)alloc((size_t)E2);
  int* bsum = (int*)alloc((size_t)2 * 1024);
  unsigned short* wb = (unsigned short*)alloc(140000);  // bf16 weight arena
  float* R = alloc((size_t)E * 64);  // bf16 feature arena (E*128 ushorts)
  unsigned short* Ru = (unsigned short*)R;
  unsigned short* emb = Ru;                                // E*128
  unsigned short* xl1b = Ru;                               // N*256 (emb dead)
  unsigned short* xr1b = Ru + (size_t)N * 256;             // N*256
  unsigned short* h1b = Ru + (size_t)N * 512;              // N*128
  unsigned short* xl2b = Ru + (size_t)N * 640;             // N*128
  unsigned short* xr2b = Ru + (size_t)N * 768;             // N*128
  unsigned short* h2b = Ru + (size_t)N * 896;              // N*128
  float* P = xout;
  float* Q = xin;

  // bf16 transposed weights
  unsigned short* epwt = wb + 0;        // [128][64]
  unsigned short* g1wlt = wb + 8192;    // [256][320]
  unsigned short* g1wrt = wb + 90112;   // [256][320]
  unsigned short* g1wet = wb + 172032;  // [256][64]
  unsigned short* g2wlt = wb + 188416;  // [128][128]
  unsigned short* g2wrt = wb + 204800;  // [128][128]
  unsigned short* g2wet = wb + 221184;  // [128][64]
  unsigned short* c1wat = wb + 229376;  // [128][128]
  unsigned short* c1wbt = wb + 245760;  // [128][128]
  unsigned short* c1wct = wb + 262144;  // [128][64]
  unsigned short* c2t = wb + 270336;    // [64][128]

  // ---- stage -1: weight prep ----
  PrepJobs J;
  auto setj = [&](int i, const float* s, unsigned short* d2, int K, int Nc,
                  int KC, int ld) {
    J.src[i] = s; J.dst[i] = d2; J.K[i] = K; J.Nc[i] = Nc; J.KC[i] = KC; J.ld[i] = ld;
  };
  setj(0, epw, epwt, 64, 128, 64, 128);
  setj(1, g1wl, g1wlt, 258, 256, 320, 256);
  setj(2, g1wr, g1wrt, 258, 256, 320, 256);
  setj(3, g1we, g1wet, 64, 256, 64, 256);
  setj(4, g2wl, g2wlt, 128, 128, 128, 128);
  setj(5, g2wr, g2wrt, 128, 128, 128, 128);
  setj(6, g2we, g2wet, 64, 128, 64, 128);
  setj(7, c1w, c1wat, 128, 128, 128, 128);
  setj(8, c1w + 128 * 128, c1wbt, 128, 128, 128, 128);
  setj(9, c1w + 256 * 128, c1wct, 64, 128, 64, 128);
  setj(10, c2w, c2t, 128, 64, 128, 64);
  prep_bt<<<dim3(11, 32), 256, 0, stream>>>(J);

  // ---- stage 0: CSR (src) + extended dst CSR (parallel scan) ----
  hipMemsetAsync(deg_src, 0, (size_t)2 * N * sizeof(int), stream);
  count_deg<<<cdiv(E, 256), 256, 0, stream>>>(src, dst, deg_src, deg_dst, E);
  scan_local<<<dim3(nb, 2), 256, 0, stream>>>(deg_src, deg_dst, row_src, row_dst,
                                              bsum, N, nb);
  scan_bsums<<<1, 1024, 0, stream>>>(bsum, nb, row_src, row_dst, N);
  scan_add<<<dim3(nb, 2), 256, 0, stream>>>(row_src, row_dst, cur_src, bsum, N, nb);
  ext_fix<<<cdiv(N + 1, 256), 256, 0, stream>>>(row_dst, row_ext, cur_ext,
                                                ext_eid, E, N);
  scatter_eid<<<cdiv(E, 256), 256, 0, stream>>>(src, dst, cur_src, cur_ext,
                                                eid_src, ext_eid, E);

  ASrc dummy{nullptr, nullptr, nullptr, 0, 0, 0, 0, 0};

  // ---- stage 1: emb = relu(ea@epw+epb) bf16; gather means ----
  {
    ASrc a{edge_attr, nullptr, nullptr, 64, 0, 0, 64, 64};
    gemm_mfma<1, 1, 0><<<dim3(cdiv(E, 64), 1), 256, 0, stream>>>(
        a, nullptr, 0, epwt, 64, epb, emb, 128, E, 64);
  }
  gather_mean<<<dim3(cdiv(N, 4), 2), 256, 0, stream>>>(
      row_src, eid_src, row_ext, ext_eid, emb, edge_attr, xout, xin, lattr, N);

  // ---- stage 2: xl1/xr1 (bf16) = xi @ g1wl / g1wr ----
  {
    ASrc a{xout, xin, node_stats, 128, 128, 2, 128, 256};
    dim3 g(cdiv(N, 64), 2);
    gemm_mfma<0, 1, 0><<<g, 256, 0, stream>>>(a, nullptr, 0, g1wlt, 320, nullptr,
                                              xl1b, 256, N, 258);
    gemm_mfma<0, 1, 0><<<g, 256, 0, stream>>>(a, nullptr, 0, g1wrt, 320, nullptr,
                                              xr1b, 256, N, 258);
  }

  // ---- stage 3: GATv2 layer 1 (H=2) ----
  attn_logits_mfma<2><<<cdiv(E2, 64), 256, 0, stream>>>(
      xl1b, xr1b, src, dst, edge_attr, lattr, g1wet, g1att, lg, E, N);
  attn_fused<2><<<cdiv(N, 4), 256, 0, stream>>>(xl1b, lg, row_ext, ext_eid, src,
                                                g1b, n1g, n1b, h1b, E, N);

  // ---- stage 4: xl2/xr2 (bf16) = h1 @ g2wl / g2wr ----
  {
    dim3 g(cdiv(N, 64), 1);
    gemm_mfma<0, 1, 1><<<g, 256, 0, stream>>>(dummy, h1b, 128, g2wlt, 128,
                                              nullptr, xl2b, 128, N, 128);
    gemm_mfma<0, 1, 1><<<g, 256, 0, stream>>>(dummy, h1b, 128, g2wrt, 128,
                                              nullptr, xr2b, 128, N, 128);
  }

  // ---- stage 5: GATv2 layer 2 (H=1) ----
  attn_logits_mfma<1><<<cdiv(E2, 64), 256, 0, stream>>>(
      xl2b, xr2b, src, dst, edge_attr, lattr, g2wet, g2att, lg, E, N);
  attn_fused<1><<<cdiv(N, 4), 256, 0, stream>>>(xl2b, lg, row_ext, ext_eid, src,
                                                g2b, n2g, n2b, h2b, E, N);

  // ---- stage 6: classifier ----
  {
    dim3 g(cdiv(N, 64), 1);
    gemm_mfma<0, 0, 1><<<g, 256, 0, stream>>>(dummy, h2b, 128, c1wat, 128,
                                              nullptr, P, 128, N, 128);
    gemm_mfma<0, 0, 1><<<g, 256, 0, stream>>>(dummy, h2b, 128, c1wbt, 128,
                                              nullptr, Q, 128, N, 128);
  }
  classifier_mfma<<<cdiv(E, 64), 256, 0, stream>>>(
      edge_attr, c1wct, src, dst, P, Q, c1b, c2t, c2b, c3w, c3b, out, E);
}